// Round 8
// baseline (906.512 us; speedup 1.0000x reference)
//
#include <hip/hip_runtime.h>
#include <hip/hip_cooperative_groups.h>
#include <math.h>

namespace cg = cooperative_groups;

#define BB 32
#define NN 1024
#define FF 10
#define DD 64
#define MM 4
#define RR 8
#define KK 20
#define BNROWS (BB*NN)   // 32768
#define GRID 512

// ---- workspace layout (float offsets) ----
#define OFF_HIT   0ull           // h_it   [B,N,D]  2097152  (dead after pool -> sc fallback)
#define OFF_XLIN  2097152ull     // x_lin  [B,N,D]  2097152
#define OFF_EIT   4194304ull     // e_it   [B,N]    32768
#define OFF_PIT   4227072ull     // pi_t   [B,M]    128
#define OFF_MIXED 4227200ull     // mixed  [B,N,D]  2097152
#define OFF_SI    6324352ull     // s_i    [B,N]    32768
#define OFF_SJ    6357120ull     // s_j    [B,N]    32768
#define OFF_GNN   7700608ull     // gnn_pre [B,N,D] 2097152
#define OFF_OUTP  9797760ull     // out_pre [B,N,D] 2097152
#define OFF_STAT  11894912ull    // stats 256 + pool num 2048 + pool den 32
#define OFF_SC    (OFF_STAT + 2560ull)  // score buffer (if ws large enough)

struct MegaArgs {
    const float *data, *gumbel, *W_cond, *b_cond, *W_ap, *b_ap, *W_av, *W_r, *b_r,
                *e_base, *lr_u, *lr_v, *W_gnn, *att_i, *att_j, *att_em_i, *att_em_j,
                *b_gnn, *bn1_g, *bn1_b, *net, *bno_g, *bno_b, *W_out, *b_out;
    float* ws;
    float* out0;
    float* sc;
    int cb;
};

__device__ __forceinline__ float wave_sum(float v) {
    #pragma unroll
    for (int off = 32; off; off >>= 1) v += __shfl_xor(v, off);
    return v;
}
__device__ __forceinline__ float wave_max(float v) {
    #pragma unroll
    for (int off = 32; off; off >>= 1) v = fmaxf(v, __shfl_xor(v, off));
    return v;
}

// ============================================================================
// Cooperative mega-kernel: all phases grid-stride, 512 blocks (2/CU guaranteed)
// ============================================================================
__global__ __launch_bounds__(256, 2) void k_mega(MegaArgs a)
{
    cg::grid_group grid = cg::this_grid();
    __shared__ __align__(16) float smem[8448];     // 33792 B (score staging peak)

    int t = threadIdx.x, w = t >> 6, lane = t & 63;
    int blk = blockIdx.x;
    int nb = gridDim.x;
    int nwaves = nb * 4;
    int gw = blk * 4 + w;

    float* ws      = a.ws;
    float* h_it    = ws + OFF_HIT;
    float* x_lin   = ws + OFF_XLIN;
    float* e_it    = ws + OFF_EIT;
    float* pi_t    = ws + OFF_PIT;
    float* mixed   = ws + OFF_MIXED;
    float* s_i     = ws + OFF_SI;
    float* s_j     = ws + OFF_SJ;
    float* gnn_pre = ws + OFF_GNN;
    float* out_pre = ws + OFF_OUTP;
    float* stats   = ws + OFF_STAT;
    float* pnum    = stats + 256;
    float* pden    = stats + 2304;
    float* out0    = a.out0;
    float* h_sys   = out0 + BB * NN;
    float* pi_soft = out0 + BB * NN + BB * DD;

    // ---------------- Phase A1: rows (h_it, x_lin, e_it) + zero accumulators ----------------
    if (blk == 0)
        for (int idx = t; idx < 2336; idx += 256) stats[idx] = 0.f;
    for (int r = gw; r < BNROWS; r += nwaves) {
        const float* dr = a.data + r * FF;
        float df[FF];
        #pragma unroll
        for (int f = 0; f < FF; f++) df[f] = dr[f];
        float h = a.b_cond[lane], x = 0.f;
        #pragma unroll
        for (int f = 0; f < FF; f++) {
            h = fmaf(df[f], a.W_cond[f * DD + lane], h);
            x = fmaf(df[f], a.W_gnn[f * DD + lane], x);
        }
        h_it[r * DD + lane] = h;
        x_lin[r * DD + lane] = x;
        float acc = a.b_ap[lane];
        #pragma unroll
        for (int e2 = 0; e2 < DD; e2++)
            acc = fmaf(__shfl(h, e2), a.W_ap[e2 * DD + lane], acc);
        float lr2 = acc > 0.f ? acc : 0.2f * acc;
        float ep = wave_sum(lr2 * a.W_av[lane]);
        if (lane == 0) e_it[r] = ep;
    }
    grid.sync();

    // ---------------- Phase A2: pool partials (256 chunks, grid-stride) ----------------
    for (int ch = blk; ch < 256; ch += nb) {
        __syncthreads();
        int b = ch >> 3, c8 = ch & 7;
        int base = b * NN + c8 * 128 + w * 32;
        float accp = 0.f, dn = 0.f;
        #pragma unroll 4
        for (int i = 0; i < 32; i++) {
            float e = e_it[base + i];
            float wgt = expf(e);
            accp = fmaf(wgt, h_it[(size_t)(base + i) * DD + lane], accp);
            dn += wgt;
        }
        float* pa = smem;          // [4][64]
        float* pd = smem + 256;    // [4]
        pa[w * 64 + lane] = accp;
        if (lane == 0) pd[w] = dn;
        __syncthreads();
        if (w == 0) {
            float s = pa[lane] + pa[64 + lane] + pa[128 + lane] + pa[192 + lane];
            atomicAdd(&pnum[b * DD + lane], s);
            if (lane == 0) atomicAdd(&pden[b], pd[0] + pd[1] + pd[2] + pd[3]);
        }
    }
    grid.sync();

    // ---------------- Phase B: routing (block 0 only) ----------------
    if (blk == 0) {
        for (int i = t; i < BB * DD; i += 256)
            h_sys[i] = pnum[i] / pden[i >> 6];
        if (t < BB) {
            int b = t;
            float inv = 1.0f / pden[b];
            float lg[MM];
            #pragma unroll
            for (int m = 0; m < MM; m++) lg[m] = a.b_r[m] + a.gumbel[b * MM + m];
            for (int d = 0; d < DD; d++) {
                float hv = pnum[b * DD + d] * inv;
                #pragma unroll
                for (int m = 0; m < MM; m++) lg[m] = fmaf(hv, a.W_r[d * MM + m], lg[m]);
            }
            float mx = fmaxf(fmaxf(lg[0], lg[1]), fmaxf(lg[2], lg[3]));
            float s = 0.f, p[MM];
            #pragma unroll
            for (int m = 0; m < MM; m++) { p[m] = expf(lg[m] - mx); s += p[m]; }
            #pragma unroll
            for (int m = 0; m < MM; m++) { p[m] /= s; pi_soft[b * MM + m] = p[m]; }
            int i1 = 0; float v1 = p[0];
            #pragma unroll
            for (int m = 1; m < MM; m++) if (p[m] > v1) { v1 = p[m]; i1 = m; }
            int i2 = -1; float v2 = -1.f;
            #pragma unroll
            for (int m = 0; m < MM; m++) if (m != i1 && p[m] > v2) { v2 = p[m]; i2 = m; }
            float norm = fmaxf(v1 + v2, 1e-12f);
            #pragma unroll
            for (int m = 0; m < MM; m++)
                pi_t[b * MM + m] = (m == i1 ? v1 : (m == i2 ? v2 : 0.f)) / norm;
        }
    }
    grid.sync();

    // ---------------- Phase C: mixed + s_i/s_j ----------------
    for (int r = gw; r < BNROWS; r += nwaves) {
        int b = r >> 10, n = r & 1023;
        float LR[MM];
        #pragma unroll
        for (int m = 0; m < MM; m++) {
            float ac = 0.f;
            #pragma unroll
            for (int rr = 0; rr < RR; rr++)
                ac = fmaf(a.lr_u[(m * NN + n) * RR + rr], a.lr_v[(m * RR + rr) * DD + lane], ac);
            LR[m] = ac;
        }
        float eb = a.e_base[n * DD + lane];
        float mx = 0.f;
        #pragma unroll
        for (int m = 0; m < MM; m++) mx = fmaf(pi_t[b * MM + m], eb + LR[m], mx);
        mixed[(size_t)r * DD + lane] = mx;
        float x = x_lin[(size_t)r * DD + lane];
        float r1 = wave_sum(x * a.att_i[lane] + mx * a.att_em_i[lane]);
        float r2 = wave_sum(x * a.att_j[lane] + mx * a.att_em_j[lane]);
        if (lane == 0) { s_i[r] = r1; s_j[r] = r2; }
    }
    grid.sync();

    // ---------------- Phase D/E chunk loop ----------------
    float* sc = a.sc;
    for (int b0 = 0; b0 < BB; b0 += a.cb) {
        int c = (BB - b0) < a.cb ? (BB - b0) : a.cb;

        // ---- D: score GEMM, 128x128 tiles, swizzled LDS (R5-verified) ----
        float* As = smem;           // 32*132
        float* Bs = smem + 4224;    // 32*132
        for (int tt = blk; tt < c * 64; tt += nb) {
            int bb = tt >> 6;
            int rr = tt & 63;
            int it = rr >> 3, jt = rr & 7;
            int i0 = it * 128, j0 = jt * 128;
            const float* mb = mixed + (size_t)(b0 + bb) * NN * DD;

            int tx = t & 15, ty = t >> 4;
            float acc[8][8];
            #pragma unroll
            for (int aa = 0; aa < 8; aa++)
                #pragma unroll
                for (int bj = 0; bj < 8; bj++) acc[aa][bj] = 0.f;

            int rowi[4], qi[4], swi[4];
            #pragma unroll
            for (int c2 = 0; c2 < 4; c2++) {
                int id = t + c2 * 256;
                rowi[c2] = (id & 15) | ((id >> 7) << 4);
                qi[c2] = (id >> 4) & 7;
                swi[c2] = ((rowi[c2] & 4) << 4) | ((rowi[c2] >> 3) << 2) | (rowi[c2] & 3);
            }
            float4 pa4[4], pb4[4];
            #pragma unroll
            for (int c2 = 0; c2 < 4; c2++) {
                pa4[c2] = *(const float4*)(mb + (size_t)(i0 + rowi[c2]) * DD + qi[c2] * 4);
                pb4[c2] = *(const float4*)(mb + (size_t)(j0 + rowi[c2]) * DD + qi[c2] * 4);
            }
            for (int hh = 0; hh < 2; hh++) {
                __syncthreads();   // protects LDS across hh and tt iterations
                #pragma unroll
                for (int c2 = 0; c2 < 4; c2++) {
                    int pos = qi[c2] * 4 * 132 + swi[c2];
                    As[pos] = pa4[c2].x; As[pos + 132] = pa4[c2].y; As[pos + 264] = pa4[c2].z; As[pos + 396] = pa4[c2].w;
                    Bs[pos] = pb4[c2].x; Bs[pos + 132] = pb4[c2].y; Bs[pos + 264] = pb4[c2].z; Bs[pos + 396] = pb4[c2].w;
                }
                __syncthreads();
                if (hh == 0) {
                    #pragma unroll
                    for (int c2 = 0; c2 < 4; c2++) {
                        pa4[c2] = *(const float4*)(mb + (size_t)(i0 + rowi[c2]) * DD + 32 + qi[c2] * 4);
                        pb4[c2] = *(const float4*)(mb + (size_t)(j0 + rowi[c2]) * DD + 32 + qi[c2] * 4);
                    }
                }
                #pragma unroll 4
                for (int d = 0; d < 32; d++) {
                    float4 a0 = *(const float4*)&As[d * 132 + ty * 4];
                    float4 a1 = *(const float4*)&As[d * 132 + 64 + ty * 4];
                    float4 b0v = *(const float4*)&Bs[d * 132 + tx * 4];
                    float4 b1v = *(const float4*)&Bs[d * 132 + 64 + tx * 4];
                    float av[8] = {a0.x, a0.y, a0.z, a0.w, a1.x, a1.y, a1.z, a1.w};
                    float bv[8] = {b0v.x, b0v.y, b0v.z, b0v.w, b1v.x, b1v.y, b1v.z, b1v.w};
                    #pragma unroll
                    for (int aa = 0; aa < 8; aa++)
                        #pragma unroll
                        for (int bj = 0; bj < 8; bj++)
                            acc[aa][bj] = fmaf(av[aa], bv[bj], acc[aa][bj]);
                }
            }
            float* outp = sc + ((size_t)bb * NN + i0 + ty * 8) * NN + j0 + tx * 8;
            #pragma unroll
            for (int aa = 0; aa < 8; aa++) {
                float4 o0 = {acc[aa][0], acc[aa][1], acc[aa][2], acc[aa][3]};
                float4 o1 = {acc[aa][4], acc[aa][5], acc[aa][6], acc[aa][7]};
                *(float4*)(outp + (size_t)aa * NN) = o0;
                *(float4*)(outp + (size_t)aa * NN + 4) = o1;
            }
        }
        grid.sync();

        // ---- E: top-20 selection + GAT + gnn stats (R5-verified) ----
        unsigned* skey = (unsigned*)smem;          // [4][64]
        int* sjjm = (int*)(smem + 256);            // [4][64]
        float* spart = smem + 512;                 // [2][4][64]
        float sl = 0.f, ql = 0.f;
        for (int lrow = gw; lrow < c * NN; lrow += nwaves) {
            int gr = (b0 << 10) + lrow;
            int b = gr >> 10, n = gr & 1023;
            const float* row = sc + (size_t)lrow * NN;

            unsigned uk[16];
            #pragma unroll
            for (int c2 = 0; c2 < 4; c2++) {
                float4 v = *(const float4*)(row + c2 * 256 + lane * 4);
                float vv[4] = {v.x, v.y, v.z, v.w};
                #pragma unroll
                for (int q = 0; q < 4; q++) {
                    unsigned u = __float_as_uint(vv[q]);
                    uk[c2 * 4 + q] = u ^ (((unsigned)((int)u >> 31)) | 0x80000000u);
                }
            }
            unsigned mxk = uk[0];
            #pragma unroll
            for (int i = 1; i < 16; i++) mxk = uk[i] > mxk ? uk[i] : mxk;
            unsigned sv = mxk;
            #pragma unroll
            for (int blk2 = 2; blk2 <= 64; blk2 <<= 1) {
                #pragma unroll
                for (int dist = blk2 >> 1; dist >= 1; dist >>= 1) {
                    unsigned pv = (unsigned)__shfl_xor((int)sv, dist);
                    bool up = (lane & blk2) == 0;
                    bool upper = (lane & dist) == 0;
                    bool g = sv > pv;
                    sv = (((g == upper) == up)) ? sv : pv;
                }
            }
            unsigned tau = (unsigned)__shfl((int)sv, 19);

            int base = 0;
            #pragma unroll
            for (int s = 0; s < 16; s++) {
                bool q = uk[s] >= tau;
                unsigned long long m = __ballot(q);
                if (q) {
                    int pos = base + __popcll(m & ((1ull << lane) - 1ull));
                    if (pos < 64) {
                        skey[w * 64 + pos] = uk[s];
                        sjjm[w * 64 + pos] = ((s >> 2) << 8) + lane * 4 + (s & 3);
                    }
                }
                base += __popcll(m);
            }
            int C = base;

            float vk = -INFINITY; int ik = 0;
            if (C <= 64) {
                unsigned ck = 0u; int cj = 0x7FFFFFFF;
                if (lane < C) { ck = skey[w * 64 + lane]; cj = sjjm[w * 64 + lane]; }
                if (C <= 32) {
                    #pragma unroll
                    for (int blk2 = 2; blk2 <= 32; blk2 <<= 1)
                        #pragma unroll
                        for (int dist = blk2 >> 1; dist >= 1; dist >>= 1) {
                            unsigned pk = (unsigned)__shfl_xor((int)ck, dist);
                            int pj = __shfl_xor(cj, dist);
                            bool up = (lane & blk2) == 0;
                            bool upper = (lane & dist) == 0;
                            bool g = (ck > pk) || (ck == pk && cj < pj);
                            bool keep = ((g == upper) == up);
                            ck = keep ? ck : pk; cj = keep ? cj : pj;
                        }
                } else {
                    #pragma unroll
                    for (int blk2 = 2; blk2 <= 64; blk2 <<= 1)
                        #pragma unroll
                        for (int dist = blk2 >> 1; dist >= 1; dist >>= 1) {
                            unsigned pk = (unsigned)__shfl_xor((int)ck, dist);
                            int pj = __shfl_xor(cj, dist);
                            bool up = (lane & blk2) == 0;
                            bool upper = (lane & dist) == 0;
                            bool g = (ck > pk) || (ck == pk && cj < pj);
                            bool keep = ((g == upper) == up);
                            ck = keep ? ck : pk; cj = keep ? cj : pj;
                        }
                }
                if (lane < KK) {
                    unsigned u = (ck & 0x80000000u) ? (ck ^ 0x80000000u) : ~ck;
                    vk = __uint_as_float(u);
                    ik = cj;
                }
            } else {
                for (int k = 0; k < KK; k++) {
                    unsigned bm = uk[0]; int bsl = 0;
                    #pragma unroll
                    for (int i = 1; i < 16; i++) if (uk[i] > bm) { bm = uk[i]; bsl = i; }
                    unsigned wm = bm;
                    #pragma unroll
                    for (int off = 32; off; off >>= 1) {
                        unsigned tt2 = (unsigned)__shfl_xor((int)wm, off);
                        wm = tt2 > wm ? tt2 : wm;
                    }
                    unsigned long long ball = __ballot(bm == wm);
                    int winner = (int)__builtin_ctzll(ball);
                    int slotw = __shfl(bsl, winner);
                    int jw = ((slotw >> 2) << 8) + winner * 4 + (slotw & 3);
                    unsigned u2 = (wm & 0x80000000u) ? (wm ^ 0x80000000u) : ~wm;
                    if (lane == k) { vk = __uint_as_float(u2); ik = jw; }
                    if (lane == winner) uk[bsl] = 0u;
                }
            }

            // GAT
            float m1 = wave_max(vk);
            float ek = (lane < KK) ? expf(vk - m1) : 0.f;
            float s1v = wave_sum(ek);
            float wk = ek / s1v;
            float si = s_i[gr], sjn = s_j[gr];
            float aat = -INFINITY;
            if (lane < KK) {
                float sjk = s_j[(b << 10) + ik];
                float t2 = si + sjk;
                aat = (ik == n) ? -INFINITY : (t2 > 0.f ? t2 : 0.2f * t2);
            }
            float tsv = si + sjn;
            float aself = tsv > 0.f ? tsv : 0.2f * tsv;
            float am = wave_max(fmaxf(aat, aself));
            float ea = (lane < KK && aat != -INFINITY) ? expf(aat - am) : 0.f;
            float es = expf(aself - am);
            float ssum = wave_sum(ea) + es;
            float wnb = (ea / ssum) * wk;
            float wself = es / ssum;
            float accg = a.b_gnn[lane] + wself * x_lin[(size_t)gr * DD + lane];
            #pragma unroll
            for (int k = 0; k < KK; k++) {
                int jk = __shfl(ik, k);
                float wv = __shfl(wnb, k);
                accg = fmaf(wv, x_lin[((size_t)(b << 10) + jk) * DD + lane], accg);
            }
            gnn_pre[(size_t)gr * DD + lane] = accg;
            sl += accg; ql = fmaf(accg, accg, ql);
        }
        __syncthreads();
        spart[w * 64 + lane] = sl;
        spart[256 + w * 64 + lane] = ql;
        __syncthreads();
        if (w == 0) {
            float S = spart[lane] + spart[64 + lane] + spart[128 + lane] + spart[192 + lane];
            float Q = spart[256 + lane] + spart[320 + lane] + spart[384 + lane] + spart[448 + lane];
            atomicAdd(&stats[lane], S);
            atomicAdd(&stats[64 + lane], Q);
        }
        grid.sync();
    }

    // ---------------- Phase F: bn1 + relu + embed mult + bno stats ----------------
    {
        int d0 = (t & 15) * 4;
        float mean4[4], rs4[4], bt4[4];
        #pragma unroll
        for (int k = 0; k < 4; k++) {
            float mu = stats[d0 + k] * (1.0f / BNROWS);
            float var = stats[64 + d0 + k] * (1.0f / BNROWS) - mu * mu;
            mean4[k] = mu;
            rs4[k] = rsqrtf(var + 1e-5f) * a.bn1_g[d0 + k];
            bt4[k] = a.bn1_b[d0 + k];
        }
        float s4[4] = {0, 0, 0, 0}, q4[4] = {0, 0, 0, 0};
        for (size_t f4 = (size_t)blk * 256 + t; f4 < (size_t)BNROWS * 16; f4 += (size_t)nb * 256) {
            float4 v = ((const float4*)gnn_pre)[f4];
            int n = ((int)(f4 >> 4)) & 1023;
            float4 nv = ((const float4*)a.net)[(size_t)n * 16 + (t & 15)];
            float vv[4] = {v.x, v.y, v.z, v.w};
            float nn2[4] = {nv.x, nv.y, nv.z, nv.w};
            float ov[4];
            #pragma unroll
            for (int k = 0; k < 4; k++) {
                float y = (vv[k] - mean4[k]) * rs4[k] + bt4[k];
                y = y > 0.f ? y : 0.f;
                float o = y * nn2[k];
                ov[k] = o;
                s4[k] += o;
                q4[k] = fmaf(o, o, q4[k]);
            }
            float4 o4 = {ov[0], ov[1], ov[2], ov[3]};
            ((float4*)out_pre)[f4] = o4;
        }
        float4* ls = (float4*)smem;            // 256 float4
        float4* lq = (float4*)(smem + 1024);   // 256 float4
        __syncthreads();
        ls[t] = make_float4(s4[0], s4[1], s4[2], s4[3]);
        lq[t] = make_float4(q4[0], q4[1], q4[2], q4[3]);
        __syncthreads();
        if (t < 16) {
            float4 S = ls[t], Q = lq[t];
            #pragma unroll
            for (int rr = 1; rr < 16; rr++) {
                float4 aa = ls[t + 16 * rr], bb = lq[t + 16 * rr];
                S.x += aa.x; S.y += aa.y; S.z += aa.z; S.w += aa.w;
                Q.x += bb.x; Q.y += bb.y; Q.z += bb.z; Q.w += bb.w;
            }
            atomicAdd(&stats[128 + t * 4 + 0], S.x);
            atomicAdd(&stats[128 + t * 4 + 1], S.y);
            atomicAdd(&stats[128 + t * 4 + 2], S.z);
            atomicAdd(&stats[128 + t * 4 + 3], S.w);
            atomicAdd(&stats[192 + t * 4 + 0], Q.x);
            atomicAdd(&stats[192 + t * 4 + 1], Q.y);
            atomicAdd(&stats[192 + t * 4 + 2], Q.z);
            atomicAdd(&stats[192 + t * 4 + 3], Q.w);
        }
    }
    grid.sync();

    // ---------------- Phase G: bn_out + relu + head ----------------
    {
        float mean = stats[128 + lane] * (1.0f / BNROWS);
        float var = stats[192 + lane] * (1.0f / BNROWS) - mean * mean;
        float rs = rsqrtf(var + 1e-5f) * a.bno_g[lane];
        float bt = a.bno_b[lane];
        float wo = a.W_out[lane];
        float bo = a.b_out[0];
        for (int r = gw; r < BNROWS; r += nwaves) {
            float y = (out_pre[(size_t)r * DD + lane] - mean) * rs + bt;
            y = y > 0.f ? y : 0.f;
            float p = wave_sum(y * wo);
            if (lane == 0) out0[r] = p + bo;
        }
    }
}

// ============================================================================
// Fallback split kernels (R5-verified, 319 us path)
// ============================================================================
__global__ __launch_bounds__(256) void k_rows(
    const float* __restrict__ data, const float* __restrict__ W_cond,
    const float* __restrict__ b_cond, const float* __restrict__ W_ap,
    const float* __restrict__ b_ap, const float* __restrict__ W_av,
    const float* __restrict__ W_gnn,
    float* __restrict__ h_it, float* __restrict__ x_lin, float* __restrict__ e_it,
    float* __restrict__ stats)
{
    if (blockIdx.x < 10) {
        int idx = blockIdx.x * 256 + threadIdx.x;
        if (idx < 2336) stats[idx] = 0.f;
    }
    int w = threadIdx.x >> 6, lane = threadIdx.x & 63;
    int r = blockIdx.x * 4 + w;
    const float* dr = data + r * FF;
    float df[FF];
    #pragma unroll
    for (int f = 0; f < FF; f++) df[f] = dr[f];
    float h = b_cond[lane], x = 0.f;
    #pragma unroll
    for (int f = 0; f < FF; f++) {
        h = fmaf(df[f], W_cond[f * DD + lane], h);
        x = fmaf(df[f], W_gnn[f * DD + lane], x);
    }
    h_it[r * DD + lane] = h;
    x_lin[r * DD + lane] = x;
    float acc = b_ap[lane];
    #pragma unroll
    for (int e2 = 0; e2 < DD; e2++)
        acc = fmaf(__shfl(h, e2), W_ap[e2 * DD + lane], acc);
    float lr = acc > 0.f ? acc : 0.2f * acc;
    float ep = wave_sum(lr * W_av[lane]);
    if (lane == 0) e_it[r] = ep;
}

__global__ __launch_bounds__(256) void k_pool2(
    const float* __restrict__ e_it, const float* __restrict__ h_it,
    float* __restrict__ num, float* __restrict__ den)
{
    int w = threadIdx.x >> 6, lane = threadIdx.x & 63;
    int b = blockIdx.x >> 3, ch = blockIdx.x & 7;
    int base = b * NN + ch * 128 + w * 32;
    float acc = 0.f, dn = 0.f;
    #pragma unroll 4
    for (int i = 0; i < 32; i++) {
        float e = e_it[base + i];
        float wgt = expf(e);
        acc = fmaf(wgt, h_it[(size_t)(base + i) * DD + lane], acc);
        dn += wgt;
    }
    __shared__ float pa[4][DD];
    __shared__ float pd[4];
    pa[w][lane] = acc;
    if (lane == 0) pd[w] = dn;
    __syncthreads();
    if (w == 0) {
        float s = pa[0][lane] + pa[1][lane] + pa[2][lane] + pa[3][lane];
        atomicAdd(&num[b * DD + lane], s);
        if (lane == 0) atomicAdd(&den[b], pd[0] + pd[1] + pd[2] + pd[3]);
    }
}

__global__ void k_route(const float* __restrict__ num, const float* __restrict__ den,
                        const float* __restrict__ W_r, const float* __restrict__ b_r,
                        const float* __restrict__ gumbel,
                        float* __restrict__ h_sys, float* __restrict__ pi_soft,
                        float* __restrict__ pi_t)
{
    int tid = threadIdx.x;
    for (int i = tid; i < BB * DD; i += 256)
        h_sys[i] = num[i] / den[i >> 6];
    if (tid >= BB) return;
    int b = tid;
    float inv = 1.0f / den[b];
    float lg[MM];
    #pragma unroll
    for (int m = 0; m < MM; m++) lg[m] = b_r[m] + gumbel[b * MM + m];
    for (int d = 0; d < DD; d++) {
        float hv = num[b * DD + d] * inv;
        #pragma unroll
        for (int m = 0; m < MM; m++) lg[m] = fmaf(hv, W_r[d * MM + m], lg[m]);
    }
    float mx = fmaxf(fmaxf(lg[0], lg[1]), fmaxf(lg[2], lg[3]));
    float s = 0.f, p[MM];
    #pragma unroll
    for (int m = 0; m < MM; m++) { p[m] = expf(lg[m] - mx); s += p[m]; }
    #pragma unroll
    for (int m = 0; m < MM; m++) { p[m] /= s; pi_soft[b * MM + m] = p[m]; }
    int i1 = 0; float v1 = p[0];
    #pragma unroll
    for (int m = 1; m < MM; m++) if (p[m] > v1) { v1 = p[m]; i1 = m; }
    int i2 = -1; float v2 = -1.f;
    #pragma unroll
    for (int m = 0; m < MM; m++) if (m != i1 && p[m] > v2) { v2 = p[m]; i2 = m; }
    float norm = fmaxf(v1 + v2, 1e-12f);
    #pragma unroll
    for (int m = 0; m < MM; m++)
        pi_t[b * MM + m] = (m == i1 ? v1 : (m == i2 ? v2 : 0.f)) / norm;
}

__global__ __launch_bounds__(256) void k_mixed(
    const float* __restrict__ e_base, const float* __restrict__ lr_u,
    const float* __restrict__ lr_v, const float* __restrict__ pi_t,
    const float* __restrict__ x_lin,
    const float* __restrict__ att_i, const float* __restrict__ att_j,
    const float* __restrict__ att_em_i, const float* __restrict__ att_em_j,
    float* __restrict__ mixed, float* __restrict__ s_i, float* __restrict__ s_j)
{
    int w = threadIdx.x >> 6, lane = threadIdx.x & 63;
    int r = blockIdx.x * 4 + w;
    int b = r >> 10, n = r & 1023;
    float LR[MM];
    #pragma unroll
    for (int m = 0; m < MM; m++) {
        float a = 0.f;
        #pragma unroll
        for (int rr = 0; rr < RR; rr++)
            a = fmaf(lr_u[(m * NN + n) * RR + rr], lr_v[(m * RR + rr) * DD + lane], a);
        LR[m] = a;
    }
    float eb = e_base[n * DD + lane];
    float mx = 0.f;
    #pragma unroll
    for (int m = 0; m < MM; m++) mx = fmaf(pi_t[b * MM + m], eb + LR[m], mx);
    mixed[(size_t)r * DD + lane] = mx;
    float x = x_lin[(size_t)r * DD + lane];
    float r1 = wave_sum(x * att_i[lane] + mx * att_em_i[lane]);
    float r2 = wave_sum(x * att_j[lane] + mx * att_em_j[lane]);
    if (lane == 0) { s_i[r] = r1; s_j[r] = r2; }
}

__global__ __launch_bounds__(256) void k_score(
    const float* __restrict__ mixed_chunk, float* __restrict__ sc)
{
    __shared__ float As[32 * 132];
    __shared__ float Bs[32 * 132];
    int t = threadIdx.x;
    int bb = blockIdx.x >> 6;
    int rr = blockIdx.x & 63;
    int it = rr >> 3, jt = rr & 7;
    int i0 = it * 128, j0 = jt * 128;
    const float* mb = mixed_chunk + (size_t)bb * NN * DD;

    int tx = t & 15, ty = t >> 4;
    float acc[8][8];
    #pragma unroll
    for (int a = 0; a < 8; a++)
        #pragma unroll
        for (int bj = 0; bj < 8; bj++) acc[a][bj] = 0.f;

    int rowi[4], qi[4], swi[4];
    #pragma unroll
    for (int c = 0; c < 4; c++) {
        int id = t + c * 256;
        rowi[c] = (id & 15) | ((id >> 7) << 4);
        qi[c] = (id >> 4) & 7;
        swi[c] = ((rowi[c] & 4) << 4) | ((rowi[c] >> 3) << 2) | (rowi[c] & 3);
    }
    float4 pa[4], pb[4];
    #pragma unroll
    for (int c = 0; c < 4; c++) {
        pa[c] = *(const float4*)(mb + (size_t)(i0 + rowi[c]) * DD + qi[c] * 4);
        pb[c] = *(const float4*)(mb + (size_t)(j0 + rowi[c]) * DD + qi[c] * 4);
    }
    for (int hh = 0; hh < 2; hh++) {
        if (hh) __syncthreads();
        #pragma unroll
        for (int c = 0; c < 4; c++) {
            int pos = qi[c] * 4 * 132 + swi[c];
            As[pos] = pa[c].x; As[pos + 132] = pa[c].y; As[pos + 264] = pa[c].z; As[pos + 396] = pa[c].w;
            Bs[pos] = pb[c].x; Bs[pos + 132] = pb[c].y; Bs[pos + 264] = pb[c].z; Bs[pos + 396] = pb[c].w;
        }
        __syncthreads();
        if (hh == 0) {
            #pragma unroll
            for (int c = 0; c < 4; c++) {
                pa[c] = *(const float4*)(mb + (size_t)(i0 + rowi[c]) * DD + 32 + qi[c] * 4);
                pb[c] = *(const float4*)(mb + (size_t)(j0 + rowi[c]) * DD + 32 + qi[c] * 4);
            }
        }
        #pragma unroll 4
        for (int d = 0; d < 32; d++) {
            float4 a0 = *(const float4*)&As[d * 132 + ty * 4];
            float4 a1 = *(const float4*)&As[d * 132 + 64 + ty * 4];
            float4 b0 = *(const float4*)&Bs[d * 132 + tx * 4];
            float4 b1 = *(const float4*)&Bs[d * 132 + 64 + tx * 4];
            float av[8] = {a0.x, a0.y, a0.z, a0.w, a1.x, a1.y, a1.z, a1.w};
            float bv[8] = {b0.x, b0.y, b0.z, b0.w, b1.x, b1.y, b1.z, b1.w};
            #pragma unroll
            for (int a = 0; a < 8; a++)
                #pragma unroll
                for (int bj = 0; bj < 8; bj++)
                    acc[a][bj] = fmaf(av[a], bv[bj], acc[a][bj]);
        }
    }
    float* out = sc + ((size_t)bb * NN + i0 + ty * 8) * NN + j0 + tx * 8;
    #pragma unroll
    for (int a = 0; a < 8; a++) {
        float4 o0 = {acc[a][0], acc[a][1], acc[a][2], acc[a][3]};
        float4 o1 = {acc[a][4], acc[a][5], acc[a][6], acc[a][7]};
        *(float4*)(out + (size_t)a * NN) = o0;
        *(float4*)(out + (size_t)a * NN + 4) = o1;
    }
}

__global__ __launch_bounds__(256) void k_selgat(
    const float* __restrict__ sc, int b0,
    const float* __restrict__ x_lin, const float* __restrict__ s_i,
    const float* __restrict__ s_j, const float* __restrict__ b_gnn,
    float* __restrict__ gnn_pre, float* __restrict__ stats)
{
    int w = threadIdx.x >> 6, lane = threadIdx.x & 63;
    int lr = blockIdx.x * 4 + w;
    int r = b0 * NN + lr;
    int b = r >> 10, n = r & 1023;
    const float* row = sc + (size_t)lr * NN;

    unsigned uk[16];
    #pragma unroll
    for (int c = 0; c < 4; c++) {
        float4 v = *(const float4*)(row + c * 256 + lane * 4);
        float vv[4] = {v.x, v.y, v.z, v.w};
        #pragma unroll
        for (int q = 0; q < 4; q++) {
            unsigned u = __float_as_uint(vv[q]);
            uk[c * 4 + q] = u ^ (((unsigned)((int)u >> 31)) | 0x80000000u);
        }
    }
    unsigned mx = uk[0];
    #pragma unroll
    for (int i = 1; i < 16; i++) mx = uk[i] > mx ? uk[i] : mx;
    unsigned sv = mx;
    #pragma unroll
    for (int blk = 2; blk <= 64; blk <<= 1) {
        #pragma unroll
        for (int dist = blk >> 1; dist >= 1; dist >>= 1) {
            unsigned pv = (unsigned)__shfl_xor((int)sv, dist);
            bool up = (lane & blk) == 0;
            bool upper = (lane & dist) == 0;
            bool g = sv > pv;
            sv = (((g == upper) == up)) ? sv : pv;
        }
    }
    unsigned tau = (unsigned)__shfl((int)sv, 19);

    __shared__ unsigned skey[4][64];
    __shared__ int sjj[4][64];
    int base = 0;
    #pragma unroll
    for (int s = 0; s < 16; s++) {
        bool q = uk[s] >= tau;
        unsigned long long m = __ballot(q);
        if (q) {
            int pos = base + __popcll(m & ((1ull << lane) - 1ull));
            if (pos < 64) {
                skey[w][pos] = uk[s];
                sjj[w][pos] = ((s >> 2) << 8) + lane * 4 + (s & 3);
            }
        }
        base += __popcll(m);
    }
    int C = base;

    float vk = -INFINITY; int ik = 0;
    if (C <= 64) {
        unsigned ck = 0u; int cj = 0x7FFFFFFF;
        if (lane < C) { ck = skey[w][lane]; cj = sjj[w][lane]; }
        if (C <= 32) {
            #pragma unroll
            for (int blk = 2; blk <= 32; blk <<= 1)
                #pragma unroll
                for (int dist = blk >> 1; dist >= 1; dist >>= 1) {
                    unsigned pk = (unsigned)__shfl_xor((int)ck, dist);
                    int pj = __shfl_xor(cj, dist);
                    bool up = (lane & blk) == 0;
                    bool upper = (lane & dist) == 0;
                    bool g = (ck > pk) || (ck == pk && cj < pj);
                    bool keep = ((g == upper) == up);
                    ck = keep ? ck : pk; cj = keep ? cj : pj;
                }
        } else {
            #pragma unroll
            for (int blk = 2; blk <= 64; blk <<= 1)
                #pragma unroll
                for (int dist = blk >> 1; dist >= 1; dist >>= 1) {
                    unsigned pk = (unsigned)__shfl_xor((int)ck, dist);
                    int pj = __shfl_xor(cj, dist);
                    bool up = (lane & blk) == 0;
                    bool upper = (lane & dist) == 0;
                    bool g = (ck > pk) || (ck == pk && cj < pj);
                    bool keep = ((g == upper) == up);
                    ck = keep ? ck : pk; cj = keep ? cj : pj;
                }
        }
        if (lane < KK) {
            unsigned u = (ck & 0x80000000u) ? (ck ^ 0x80000000u) : ~ck;
            vk = __uint_as_float(u);
            ik = cj;
        }
    } else {
        for (int k = 0; k < KK; k++) {
            unsigned bm = uk[0]; int bsl = 0;
            #pragma unroll
            for (int i = 1; i < 16; i++) if (uk[i] > bm) { bm = uk[i]; bsl = i; }
            unsigned wm = bm;
            #pragma unroll
            for (int off = 32; off; off >>= 1) {
                unsigned tt = (unsigned)__shfl_xor((int)wm, off);
                wm = tt > wm ? tt : wm;
            }
            unsigned long long ball = __ballot(bm == wm);
            int winner = (int)__builtin_ctzll(ball);
            int slotw = __shfl(bsl, winner);
            int jw = ((slotw >> 2) << 8) + winner * 4 + (slotw & 3);
            unsigned u2 = (wm & 0x80000000u) ? (wm ^ 0x80000000u) : ~wm;
            if (lane == k) { vk = __uint_as_float(u2); ik = jw; }
            if (lane == winner) uk[bsl] = 0u;
        }
    }

    float m1 = wave_max(vk);
    float ek = (lane < KK) ? expf(vk - m1) : 0.f;
    float s1v = wave_sum(ek);
    float wk = ek / s1v;
    float si = s_i[r], sjn = s_j[r];
    float a = -INFINITY;
    if (lane < KK) {
        float sjk = s_j[(b << 10) + ik];
        float t2 = si + sjk;
        a = (ik == n) ? -INFINITY : (t2 > 0.f ? t2 : 0.2f * t2);
    }
    float ts = si + sjn;
    float aself = ts > 0.f ? ts : 0.2f * ts;
    float am = wave_max(fmaxf(a, aself));
    float ea = (lane < KK && a != -INFINITY) ? expf(a - am) : 0.f;
    float es = expf(aself - am);
    float ssum = wave_sum(ea) + es;
    float wnb = (ea / ssum) * wk;
    float wself = es / ssum;
    float accg = b_gnn[lane] + wself * x_lin[(size_t)r * DD + lane];
    #pragma unroll
    for (int k = 0; k < KK; k++) {
        int jk = __shfl(ik, k);
        float wv = __shfl(wnb, k);
        accg = fmaf(wv, x_lin[((size_t)(b << 10) + jk) * DD + lane], accg);
    }
    gnn_pre[(size_t)r * DD + lane] = accg;

    __shared__ float spart[2][4][64];
    spart[0][w][lane] = accg;
    spart[1][w][lane] = accg * accg;
    __syncthreads();
    if (w == 0) {
        float S = spart[0][0][lane] + spart[0][1][lane] + spart[0][2][lane] + spart[0][3][lane];
        float Q = spart[1][0][lane] + spart[1][1][lane] + spart[1][2][lane] + spart[1][3][lane];
        atomicAdd(&stats[lane], S);
        atomicAdd(&stats[64 + lane], Q);
    }
}

__global__ __launch_bounds__(256) void k_bn1(
    const float* __restrict__ gnn_pre, float* __restrict__ stats,
    const float* __restrict__ gamma, const float* __restrict__ beta,
    const float* __restrict__ net, float* __restrict__ out_pre)
{
    int tid = threadIdx.x;
    int d0 = (tid & 15) * 4;
    float mean4[4], rs4[4], bt4[4];
    #pragma unroll
    for (int k = 0; k < 4; k++) {
        float mu = stats[d0 + k] * (1.0f / BNROWS);
        float var = stats[64 + d0 + k] * (1.0f / BNROWS) - mu * mu;
        mean4[k] = mu;
        rs4[k] = rsqrtf(var + 1e-5f) * gamma[d0 + k];
        bt4[k] = beta[d0 + k];
    }
    float s4[4] = {0, 0, 0, 0}, q4[4] = {0, 0, 0, 0};
    size_t base4 = (size_t)blockIdx.x * 2048;
    #pragma unroll
    for (int i = 0; i < 8; i++) {
        size_t f4 = base4 + (size_t)i * 256 + tid;
        float4 v = ((const float4*)gnn_pre)[f4];
        int n = ((int)(f4 >> 4)) & 1023;
        float4 nv = ((const float4*)net)[(size_t)n * 16 + (tid & 15)];
        float vv[4] = {v.x, v.y, v.z, v.w};
        float nn2[4] = {nv.x, nv.y, nv.z, nv.w};
        float ov[4];
        #pragma unroll
        for (int k = 0; k < 4; k++) {
            float y = (vv[k] - mean4[k]) * rs4[k] + bt4[k];
            y = y > 0.f ? y : 0.f;
            float o = y * nn2[k];
            ov[k] = o;
            s4[k] += o;
            q4[k] = fmaf(o, o, q4[k]);
        }
        float4 o4 = {ov[0], ov[1], ov[2], ov[3]};
        ((float4*)out_pre)[f4] = o4;
    }
    __shared__ float4 ls[256], lq[256];
    ls[tid] = make_float4(s4[0], s4[1], s4[2], s4[3]);
    lq[tid] = make_float4(q4[0], q4[1], q4[2], q4[3]);
    __syncthreads();
    if (tid < 16) {
        float4 S = ls[tid], Q = lq[tid];
        #pragma unroll
        for (int rr = 1; rr < 16; rr++) {
            float4 a = ls[tid + 16 * rr], b = lq[tid + 16 * rr];
            S.x += a.x; S.y += a.y; S.z += a.z; S.w += a.w;
            Q.x += b.x; Q.y += b.y; Q.z += b.z; Q.w += b.w;
        }
        atomicAdd(&stats[128 + tid * 4 + 0], S.x);
        atomicAdd(&stats[128 + tid * 4 + 1], S.y);
        atomicAdd(&stats[128 + tid * 4 + 2], S.z);
        atomicAdd(&stats[128 + tid * 4 + 3], S.w);
        atomicAdd(&stats[192 + tid * 4 + 0], Q.x);
        atomicAdd(&stats[192 + tid * 4 + 1], Q.y);
        atomicAdd(&stats[192 + tid * 4 + 2], Q.z);
        atomicAdd(&stats[192 + tid * 4 + 3], Q.w);
    }
}

__global__ __launch_bounds__(256) void k_head(
    const float* __restrict__ out_pre, const float* __restrict__ stats,
    const float* __restrict__ gamma, const float* __restrict__ beta,
    const float* __restrict__ W_out, const float* __restrict__ b_out,
    float* __restrict__ out)
{
    int w = threadIdx.x >> 6, lane = threadIdx.x & 63;
    int r = blockIdx.x * 4 + w;
    float mean = stats[lane] * (1.0f / BNROWS);
    float var = stats[DD + lane] * (1.0f / BNROWS) - mean * mean;
    float rs = rsqrtf(var + 1e-5f);
    float y = (out_pre[(size_t)r * DD + lane] - mean) * rs * gamma[lane] + beta[lane];
    y = y > 0.f ? y : 0.f;
    float p = wave_sum(y * W_out[lane]);
    if (lane == 0) out[r] = p + b_out[0];
}

extern "C" void kernel_launch(void* const* d_in, const int* in_sizes, int n_in,
                              void* d_out, int out_size, void* d_ws, size_t ws_size,
                              hipStream_t stream)
{
    MegaArgs a;
    a.data     = (const float*)d_in[0];
    a.gumbel   = (const float*)d_in[1];
    a.W_cond   = (const float*)d_in[2];
    a.b_cond   = (const float*)d_in[3];
    a.W_ap     = (const float*)d_in[4];
    a.b_ap     = (const float*)d_in[5];
    a.W_av     = (const float*)d_in[6];
    a.W_r      = (const float*)d_in[7];
    a.b_r      = (const float*)d_in[8];
    a.e_base   = (const float*)d_in[9];
    a.lr_u     = (const float*)d_in[10];
    a.lr_v     = (const float*)d_in[11];
    a.W_gnn    = (const float*)d_in[12];
    a.att_i    = (const float*)d_in[13];
    a.att_j    = (const float*)d_in[14];
    a.att_em_i = (const float*)d_in[15];
    a.att_em_j = (const float*)d_in[16];
    a.b_gnn    = (const float*)d_in[17];
    a.bn1_g    = (const float*)d_in[18];
    a.bn1_b    = (const float*)d_in[19];
    a.net      = (const float*)d_in[20];
    a.bno_g    = (const float*)d_in[21];
    a.bno_b    = (const float*)d_in[22];
    a.W_out    = (const float*)d_in[23];
    a.b_out    = (const float*)d_in[24];
    a.ws   = (float*)d_ws;
    a.out0 = (float*)d_out;

    size_t ws_floats = ws_size / 4;
    size_t avail = ws_floats > OFF_SC ? ws_floats - OFF_SC : 0;
    int cb = (int)(avail / (size_t)(NN * NN));
    if (cb > BB) cb = BB;
    float* sc = a.ws + OFF_SC;
    if (cb < 1) { cb = 2; sc = a.ws + OFF_HIT; }   // h_it dead after pool phase
    a.sc = sc;
    a.cb = cb;

    void* params[] = { (void*)&a };
    hipError_t err = hipLaunchCooperativeKernel((const void*)k_mega, dim3(GRID), dim3(256),
                                                params, 0, stream);
    if (err != hipSuccess) {
        // ---- fallback: R5 split-kernel path ----
        float* ws = a.ws;
        float* h_it    = ws + OFF_HIT;
        float* x_lin   = ws + OFF_XLIN;
        float* e_it    = ws + OFF_EIT;
        float* pi_t    = ws + OFF_PIT;
        float* mixed   = ws + OFF_MIXED;
        float* s_i     = ws + OFF_SI;
        float* s_j     = ws + OFF_SJ;
        float* gnn_pre = ws + OFF_GNN;
        float* out_pre = ws + OFF_OUTP;
        float* stats   = ws + OFF_STAT;
        float* pnum    = stats + 256;
        float* pden    = stats + 2304;
        float* out0    = (float*)d_out;
        float* h_sys   = out0 + BB * NN;
        float* pi_soft = out0 + BB * NN + BB * DD;

        k_rows<<<BNROWS / 4, 256, 0, stream>>>(a.data, a.W_cond, a.b_cond, a.W_ap, a.b_ap,
                                               a.W_av, a.W_gnn, h_it, x_lin, e_it, stats);
        k_pool2<<<BB * 8, 256, 0, stream>>>(e_it, h_it, pnum, pden);
        k_route<<<1, 256, 0, stream>>>(pnum, pden, a.W_r, a.b_r, a.gumbel, h_sys, pi_soft, pi_t);
        k_mixed<<<BNROWS / 4, 256, 0, stream>>>(a.e_base, a.lr_u, a.lr_v, pi_t, x_lin,
                                                a.att_i, a.att_j, a.att_em_i, a.att_em_j,
                                                mixed, s_i, s_j);
        for (int b0 = 0; b0 < BB; b0 += cb) {
            int c = (BB - b0) < cb ? (BB - b0) : cb;
            k_score<<<c * 64, 256, 0, stream>>>(mixed + (size_t)b0 * NN * DD, sc);
            k_selgat<<<c * 256, 256, 0, stream>>>(sc, b0, x_lin, s_i, s_j, a.b_gnn,
                                                  gnn_pre, stats);
        }
        k_bn1<<<256, 256, 0, stream>>>(gnn_pre, stats, a.bn1_g, a.bn1_b, a.net, out_pre);
        k_head<<<BNROWS / 4, 256, 0, stream>>>(out_pre, stats + 128, a.bno_g, a.bno_b,
                                               a.W_out, a.b_out, out0);
    }
}

// Round 9
// 542.365 us; speedup vs baseline: 1.6714x; 1.6714x over previous
//
#include <hip/hip_runtime.h>
#include <math.h>

#define BB 32
#define NN 1024
#define FF 10
#define DD 64
#define MM 4
#define RR 8
#define KK 20
#define BNROWS (BB*NN)   // 32768

// ---- workspace layout (float offsets) ----
#define OFF_HIT   0ull           // free region (sc fallback)  2097152
#define OFF_XLIN  2097152ull     // x_lin  [B,N,D]  2097152
#define OFF_MIXED 4227200ull     // mixed  [B,N,D]  2097152
#define OFF_SI    6324352ull     // s_i    [B,N]    32768
#define OFF_SJ    6357120ull     // s_j    [B,N]    32768
#define OFF_GNN   7700608ull     // gnn_pre [B,N,D] 2097152
#define OFF_OUTP  9797760ull     // out_pre [B,N,D] 2097152
#define OFF_STAT  11894912ull    // stats 256 + pool num 2048 + pool den 32
#define OFF_SC    (OFF_STAT + 2560ull)  // score buffer (if ws large enough)

__device__ __forceinline__ float wave_sum(float v) {
    #pragma unroll
    for (int off = 32; off; off >>= 1) v += __shfl_xor(v, off);
    return v;
}
__device__ __forceinline__ float wave_max(float v) {
    #pragma unroll
    for (int off = 32; off; off >>= 1) v = fmaxf(v, __shfl_xor(v, off));
    return v;
}

// ---------------- K1: rows (x_lin) + fused attention-pool partials ----------------
// wave per row; pool weight exp(e) applied in-register, block-reduced, atomically
// accumulated into pnum/pden. h_it/e_it never touch memory.
__global__ __launch_bounds__(256) void k_rows(
    const float* __restrict__ data, const float* __restrict__ W_cond,
    const float* __restrict__ b_cond, const float* __restrict__ W_ap,
    const float* __restrict__ b_ap, const float* __restrict__ W_av,
    const float* __restrict__ W_gnn,
    float* __restrict__ x_lin, float* __restrict__ pnum, float* __restrict__ pden)
{
    int w = threadIdx.x >> 6, lane = threadIdx.x & 63;
    int r = blockIdx.x * 4 + w;               // 4 rows/block, same b (1024 % 4 == 0)
    int b = r >> 10;
    const float* dr = data + r * FF;
    float df[FF];
    #pragma unroll
    for (int f = 0; f < FF; f++) df[f] = dr[f];
    float h = b_cond[lane], x = 0.f;
    #pragma unroll
    for (int f = 0; f < FF; f++) {
        h = fmaf(df[f], W_cond[f * DD + lane], h);
        x = fmaf(df[f], W_gnn[f * DD + lane], x);
    }
    x_lin[r * DD + lane] = x;
    float acc = b_ap[lane];
    #pragma unroll
    for (int e2 = 0; e2 < DD; e2++)
        acc = fmaf(__shfl(h, e2), W_ap[e2 * DD + lane], acc);
    float lr = acc > 0.f ? acc : 0.2f * acc;
    float ep = wave_sum(lr * W_av[lane]);     // all lanes hold e_it[r]
    float wgt = expf(ep);

    __shared__ float pa[4][DD];
    __shared__ float pd[4];
    pa[w][lane] = wgt * h;
    if (lane == 0) pd[w] = wgt;
    __syncthreads();
    if (w == 0) {
        float s = pa[0][lane] + pa[1][lane] + pa[2][lane] + pa[3][lane];
        atomicAdd(&pnum[b * DD + lane], s);
        if (lane == 0) atomicAdd(&pden[b], pd[0] + pd[1] + pd[2] + pd[3]);
    }
}

// ---------------- K2: mixed + s_i/s_j, routing computed inline per block ----------------
__global__ __launch_bounds__(256) void k_mixed(
    const float* __restrict__ e_base, const float* __restrict__ lr_u,
    const float* __restrict__ lr_v,
    const float* __restrict__ pnum, const float* __restrict__ pden,
    const float* __restrict__ gumbel, const float* __restrict__ W_r,
    const float* __restrict__ b_r,
    const float* __restrict__ x_lin,
    const float* __restrict__ att_i, const float* __restrict__ att_j,
    const float* __restrict__ att_em_i, const float* __restrict__ att_em_j,
    float* __restrict__ mixed, float* __restrict__ s_i, float* __restrict__ s_j,
    float* __restrict__ h_sys, float* __restrict__ pi_soft)
{
    int t = threadIdx.x, w = t >> 6, lane = t & 63;
    int r = blockIdx.x * 4 + w;
    int b = r >> 10, n = r & 1023;

    // --- routing for this block's b (redundant, deterministic -> identical) ---
    float inv = 1.0f / pden[b];
    float lg[MM];
    #pragma unroll
    for (int m = 0; m < MM; m++) lg[m] = b_r[m] + gumbel[b * MM + m];
    for (int d = 0; d < DD; d++) {
        float hv = pnum[b * DD + d] * inv;
        #pragma unroll
        for (int m = 0; m < MM; m++) lg[m] = fmaf(hv, W_r[d * MM + m], lg[m]);
    }
    float mxl = fmaxf(fmaxf(lg[0], lg[1]), fmaxf(lg[2], lg[3]));
    float sp = 0.f, p[MM];
    #pragma unroll
    for (int m = 0; m < MM; m++) { p[m] = expf(lg[m] - mxl); sp += p[m]; }
    #pragma unroll
    for (int m = 0; m < MM; m++) p[m] /= sp;
    int i1 = 0; float v1 = p[0];
    #pragma unroll
    for (int m = 1; m < MM; m++) if (p[m] > v1) { v1 = p[m]; i1 = m; }
    int i2 = -1; float v2 = -1.f;
    #pragma unroll
    for (int m = 0; m < MM; m++) if (m != i1 && p[m] > v2) { v2 = p[m]; i2 = m; }
    float norm = fmaxf(v1 + v2, 1e-12f);
    float pt[MM];
    #pragma unroll
    for (int m = 0; m < MM; m++)
        pt[m] = (m == i1 ? v1 : (m == i2 ? v2 : 0.f)) / norm;

    // --- block 0 emits h_sys + pi_soft outputs (old k_route body) ---
    if (blockIdx.x == 0) {
        for (int i = t; i < BB * DD; i += 256)
            h_sys[i] = pnum[i] / pden[i >> 6];
        if (t < BB) {
            int b2 = t;
            float inv2 = 1.0f / pden[b2];
            float lg2[MM];
            #pragma unroll
            for (int m = 0; m < MM; m++) lg2[m] = b_r[m] + gumbel[b2 * MM + m];
            for (int d = 0; d < DD; d++) {
                float hv = pnum[b2 * DD + d] * inv2;
                #pragma unroll
                for (int m = 0; m < MM; m++) lg2[m] = fmaf(hv, W_r[d * MM + m], lg2[m]);
            }
            float mx2 = fmaxf(fmaxf(lg2[0], lg2[1]), fmaxf(lg2[2], lg2[3]));
            float s2 = 0.f, p2[MM];
            #pragma unroll
            for (int m = 0; m < MM; m++) { p2[m] = expf(lg2[m] - mx2); s2 += p2[m]; }
            #pragma unroll
            for (int m = 0; m < MM; m++) pi_soft[b2 * MM + m] = p2[m] / s2;
        }
    }

    // --- mixed + s_i/s_j ---
    float LR[MM];
    #pragma unroll
    for (int m = 0; m < MM; m++) {
        float a = 0.f;
        #pragma unroll
        for (int rr = 0; rr < RR; rr++)
            a = fmaf(lr_u[(m * NN + n) * RR + rr], lr_v[(m * RR + rr) * DD + lane], a);
        LR[m] = a;
    }
    float eb = e_base[n * DD + lane];
    float mx = 0.f;
    #pragma unroll
    for (int m = 0; m < MM; m++) mx = fmaf(pt[m], eb + LR[m], mx);
    mixed[(size_t)r * DD + lane] = mx;
    float x = x_lin[(size_t)r * DD + lane];
    float r1 = wave_sum(x * att_i[lane] + mx * att_em_i[lane]);
    float r2 = wave_sum(x * att_j[lane] + mx * att_em_j[lane]);
    if (lane == 0) { s_i[r] = r1; s_j[r] = r2; }
}

// ---------------- K3: score GEMM, 128x128 tile, K in four 16-wide stages ----------------
// LDS 16.9 KB -> ~5 blocks/CU. Same per-thread fmaf order as R5 (bit-identical scores).
__global__ __launch_bounds__(256) void k_score(
    const float* __restrict__ mixed_chunk, float* __restrict__ sc)
{
    __shared__ float As[16 * 132];
    __shared__ float Bs[16 * 132];
    int t = threadIdx.x;
    int bb = blockIdx.x >> 6;
    int rr = blockIdx.x & 63;
    int it = rr >> 3, jt = rr & 7;
    int i0 = it * 128, j0 = jt * 128;
    const float* mb = mixed_chunk + (size_t)bb * NN * DD;

    int tx = t & 15, ty = t >> 4;
    float acc[8][8];
    #pragma unroll
    for (int a = 0; a < 8; a++)
        #pragma unroll
        for (int bj = 0; bj < 8; bj++) acc[a][bj] = 0.f;

    int rowi[2], qi[2], swi[2];
    #pragma unroll
    for (int c = 0; c < 2; c++) {
        int id = t + c * 256;                 // 0..511
        qi[c] = (id >> 4) & 3;
        rowi[c] = (id & 15) | ((id >> 6) << 4);
        swi[c] = ((rowi[c] & 4) << 4) | ((rowi[c] >> 3) << 2) | (rowi[c] & 3);
    }
    float4 pa[2], pb[2];
    #pragma unroll
    for (int c = 0; c < 2; c++) {             // prefetch stage 0
        pa[c] = *(const float4*)(mb + (size_t)(i0 + rowi[c]) * DD + qi[c] * 4);
        pb[c] = *(const float4*)(mb + (size_t)(j0 + rowi[c]) * DD + qi[c] * 4);
    }
    #pragma unroll
    for (int st = 0; st < 4; st++) {
        if (st) __syncthreads();
        #pragma unroll
        for (int c = 0; c < 2; c++) {
            int pos = qi[c] * 4 * 132 + swi[c];
            As[pos] = pa[c].x; As[pos + 132] = pa[c].y; As[pos + 264] = pa[c].z; As[pos + 396] = pa[c].w;
            Bs[pos] = pb[c].x; Bs[pos + 132] = pb[c].y; Bs[pos + 264] = pb[c].z; Bs[pos + 396] = pb[c].w;
        }
        __syncthreads();
        if (st < 3) {                          // prefetch next stage during compute
            #pragma unroll
            for (int c = 0; c < 2; c++) {
                pa[c] = *(const float4*)(mb + (size_t)(i0 + rowi[c]) * DD + (st + 1) * 16 + qi[c] * 4);
                pb[c] = *(const float4*)(mb + (size_t)(j0 + rowi[c]) * DD + (st + 1) * 16 + qi[c] * 4);
            }
        }
        #pragma unroll 4
        for (int d = 0; d < 16; d++) {
            float4 a0 = *(const float4*)&As[d * 132 + ty * 4];        // rows ty*8+0..3
            float4 a1 = *(const float4*)&As[d * 132 + 64 + ty * 4];   // rows ty*8+4..7
            float4 b0 = *(const float4*)&Bs[d * 132 + tx * 4];
            float4 b1 = *(const float4*)&Bs[d * 132 + 64 + tx * 4];
            float av[8] = {a0.x, a0.y, a0.z, a0.w, a1.x, a1.y, a1.z, a1.w};
            float bv[8] = {b0.x, b0.y, b0.z, b0.w, b1.x, b1.y, b1.z, b1.w};
            #pragma unroll
            for (int a = 0; a < 8; a++)
                #pragma unroll
                for (int bj = 0; bj < 8; bj++)
                    acc[a][bj] = fmaf(av[a], bv[bj], acc[a][bj]);
        }
    }

    float* out = sc + ((size_t)bb * NN + i0 + ty * 8) * NN + j0 + tx * 8;
    #pragma unroll
    for (int a = 0; a < 8; a++) {
        float4 o0 = {acc[a][0], acc[a][1], acc[a][2], acc[a][3]};
        float4 o1 = {acc[a][4], acc[a][5], acc[a][6], acc[a][7]};
        *(float4*)(out + (size_t)a * NN) = o0;
        *(float4*)(out + (size_t)a * NN + 4) = o1;
    }
}

// ---------------- K4: fused top-20 selection + GAT + gnn stats ----------------
__global__ __launch_bounds__(256) void k_selgat(
    const float* __restrict__ sc, int b0,
    const float* __restrict__ x_lin, const float* __restrict__ s_i,
    const float* __restrict__ s_j, const float* __restrict__ b_gnn,
    float* __restrict__ gnn_pre, float* __restrict__ stats)
{
    int w = threadIdx.x >> 6, lane = threadIdx.x & 63;
    int lr = blockIdx.x * 4 + w;
    int r = b0 * NN + lr;
    int b = r >> 10, n = r & 1023;
    const float* row = sc + (size_t)lr * NN;

    unsigned uk[16];
    #pragma unroll
    for (int c = 0; c < 4; c++) {
        float4 v = *(const float4*)(row + c * 256 + lane * 4);
        float vv[4] = {v.x, v.y, v.z, v.w};
        #pragma unroll
        for (int q = 0; q < 4; q++) {
            unsigned u = __float_as_uint(vv[q]);
            uk[c * 4 + q] = u ^ (((unsigned)((int)u >> 31)) | 0x80000000u);
        }
    }
    unsigned mx = uk[0];
    #pragma unroll
    for (int i = 1; i < 16; i++) mx = uk[i] > mx ? uk[i] : mx;
    unsigned sv = mx;
    #pragma unroll
    for (int blk = 2; blk <= 64; blk <<= 1) {
        #pragma unroll
        for (int dist = blk >> 1; dist >= 1; dist >>= 1) {
            unsigned pv = (unsigned)__shfl_xor((int)sv, dist);
            bool up = (lane & blk) == 0;
            bool upper = (lane & dist) == 0;
            bool g = sv > pv;
            sv = (((g == upper) == up)) ? sv : pv;
        }
    }
    unsigned tau = (unsigned)__shfl((int)sv, 19);

    __shared__ unsigned skey[4][64];
    __shared__ int sjj[4][64];
    int base = 0;
    #pragma unroll
    for (int s = 0; s < 16; s++) {
        bool q = uk[s] >= tau;
        unsigned long long m = __ballot(q);
        if (q) {
            int pos = base + __popcll(m & ((1ull << lane) - 1ull));
            if (pos < 64) {
                skey[w][pos] = uk[s];
                sjj[w][pos] = ((s >> 2) << 8) + lane * 4 + (s & 3);
            }
        }
        base += __popcll(m);
    }
    int C = base;

    float vk = -INFINITY; int ik = 0;
    if (C <= 64) {
        unsigned ck = 0u; int cj = 0x7FFFFFFF;
        if (lane < C) { ck = skey[w][lane]; cj = sjj[w][lane]; }
        if (C <= 32) {
            #pragma unroll
            for (int blk = 2; blk <= 32; blk <<= 1)
                #pragma unroll
                for (int dist = blk >> 1; dist >= 1; dist >>= 1) {
                    unsigned pk = (unsigned)__shfl_xor((int)ck, dist);
                    int pj = __shfl_xor(cj, dist);
                    bool up = (lane & blk) == 0;
                    bool upper = (lane & dist) == 0;
                    bool g = (ck > pk) || (ck == pk && cj < pj);
                    bool keep = ((g == upper) == up);
                    ck = keep ? ck : pk; cj = keep ? cj : pj;
                }
        } else {
            #pragma unroll
            for (int blk = 2; blk <= 64; blk <<= 1)
                #pragma unroll
                for (int dist = blk >> 1; dist >= 1; dist >>= 1) {
                    unsigned pk = (unsigned)__shfl_xor((int)ck, dist);
                    int pj = __shfl_xor(cj, dist);
                    bool up = (lane & blk) == 0;
                    bool upper = (lane & dist) == 0;
                    bool g = (ck > pk) || (ck == pk && cj < pj);
                    bool keep = ((g == upper) == up);
                    ck = keep ? ck : pk; cj = keep ? cj : pj;
                }
        }
        if (lane < KK) {
            unsigned u = (ck & 0x80000000u) ? (ck ^ 0x80000000u) : ~ck;
            vk = __uint_as_float(u);
            ik = cj;
        }
    } else {
        for (int k = 0; k < KK; k++) {
            unsigned bm = uk[0]; int bsl = 0;
            #pragma unroll
            for (int i = 1; i < 16; i++) if (uk[i] > bm) { bm = uk[i]; bsl = i; }
            unsigned wm = bm;
            #pragma unroll
            for (int off = 32; off; off >>= 1) {
                unsigned tt = (unsigned)__shfl_xor((int)wm, off);
                wm = tt > wm ? tt : wm;
            }
            unsigned long long ball = __ballot(bm == wm);
            int winner = (int)__builtin_ctzll(ball);
            int slotw = __shfl(bsl, winner);
            int jw = ((slotw >> 2) << 8) + winner * 4 + (slotw & 3);
            unsigned u2 = (wm & 0x80000000u) ? (wm ^ 0x80000000u) : ~wm;
            if (lane == k) { vk = __uint_as_float(u2); ik = jw; }
            if (lane == winner) uk[bsl] = 0u;
        }
    }

    float m1 = wave_max(vk);
    float ek = (lane < KK) ? expf(vk - m1) : 0.f;
    float s1v = wave_sum(ek);
    float wk = ek / s1v;
    float si = s_i[r], sjn = s_j[r];
    float a = -INFINITY;
    if (lane < KK) {
        float sjk = s_j[(b << 10) + ik];
        float t2 = si + sjk;
        a = (ik == n) ? -INFINITY : (t2 > 0.f ? t2 : 0.2f * t2);
    }
    float ts = si + sjn;
    float aself = ts > 0.f ? ts : 0.2f * ts;
    float am = wave_max(fmaxf(a, aself));
    float ea = (lane < KK && a != -INFINITY) ? expf(a - am) : 0.f;
    float es = expf(aself - am);
    float ssum = wave_sum(ea) + es;
    float wnb = (ea / ssum) * wk;
    float wself = es / ssum;
    float accg = b_gnn[lane] + wself * x_lin[(size_t)r * DD + lane];
    #pragma unroll
    for (int k = 0; k < KK; k++) {
        int jk = __shfl(ik, k);
        float wv = __shfl(wnb, k);
        accg = fmaf(wv, x_lin[((size_t)(b << 10) + jk) * DD + lane], accg);
    }
    gnn_pre[(size_t)r * DD + lane] = accg;

    __shared__ float spart[2][4][64];
    spart[0][w][lane] = accg;
    spart[1][w][lane] = accg * accg;
    __syncthreads();
    if (w == 0) {
        float S = spart[0][0][lane] + spart[0][1][lane] + spart[0][2][lane] + spart[0][3][lane];
        float Q = spart[1][0][lane] + spart[1][1][lane] + spart[1][2][lane] + spart[1][3][lane];
        atomicAdd(&stats[lane], S);
        atomicAdd(&stats[64 + lane], Q);
    }
}

// ---------------- K5: bn1 + relu + embed multiply (+ bno stats partials) ----------------
__global__ __launch_bounds__(256) void k_bn1(
    const float* __restrict__ gnn_pre, float* __restrict__ stats,
    const float* __restrict__ gamma, const float* __restrict__ beta,
    const float* __restrict__ net, float* __restrict__ out_pre)
{
    int tid = threadIdx.x;
    int d0 = (tid & 15) * 4;
    float mean4[4], rs4[4], bt4[4];
    #pragma unroll
    for (int k = 0; k < 4; k++) {
        float mu = stats[d0 + k] * (1.0f / BNROWS);
        float var = stats[64 + d0 + k] * (1.0f / BNROWS) - mu * mu;
        mean4[k] = mu;
        rs4[k] = rsqrtf(var + 1e-5f) * gamma[d0 + k];
        bt4[k] = beta[d0 + k];
    }
    float s4[4] = {0, 0, 0, 0}, q4[4] = {0, 0, 0, 0};
    size_t base4 = (size_t)blockIdx.x * 2048;
    #pragma unroll
    for (int i = 0; i < 8; i++) {
        size_t f4 = base4 + (size_t)i * 256 + tid;
        float4 v = ((const float4*)gnn_pre)[f4];
        int n = ((int)(f4 >> 4)) & 1023;
        float4 nv = ((const float4*)net)[(size_t)n * 16 + (tid & 15)];
        float vv[4] = {v.x, v.y, v.z, v.w};
        float nn2[4] = {nv.x, nv.y, nv.z, nv.w};
        float ov[4];
        #pragma unroll
        for (int k = 0; k < 4; k++) {
            float y = (vv[k] - mean4[k]) * rs4[k] + bt4[k];
            y = y > 0.f ? y : 0.f;
            float o = y * nn2[k];
            ov[k] = o;
            s4[k] += o;
            q4[k] = fmaf(o, o, q4[k]);
        }
        float4 o4 = {ov[0], ov[1], ov[2], ov[3]};
        ((float4*)out_pre)[f4] = o4;
    }
    __shared__ float4 ls[256], lq[256];
    ls[tid] = make_float4(s4[0], s4[1], s4[2], s4[3]);
    lq[tid] = make_float4(q4[0], q4[1], q4[2], q4[3]);
    __syncthreads();
    if (tid < 16) {
        float4 S = ls[tid], Q = lq[tid];
        #pragma unroll
        for (int rr = 1; rr < 16; rr++) {
            float4 a = ls[tid + 16 * rr], b = lq[tid + 16 * rr];
            S.x += a.x; S.y += a.y; S.z += a.z; S.w += a.w;
            Q.x += b.x; Q.y += b.y; Q.z += b.z; Q.w += b.w;
        }
        atomicAdd(&stats[128 + tid * 4 + 0], S.x);
        atomicAdd(&stats[128 + tid * 4 + 1], S.y);
        atomicAdd(&stats[128 + tid * 4 + 2], S.z);
        atomicAdd(&stats[128 + tid * 4 + 3], S.w);
        atomicAdd(&stats[192 + tid * 4 + 0], Q.x);
        atomicAdd(&stats[192 + tid * 4 + 1], Q.y);
        atomicAdd(&stats[192 + tid * 4 + 2], Q.z);
        atomicAdd(&stats[192 + tid * 4 + 3], Q.w);
    }
}

// ---------------- K6: bn_out + relu + head ----------------
__global__ __launch_bounds__(256) void k_head(
    const float* __restrict__ out_pre, const float* __restrict__ stats,
    const float* __restrict__ gamma, const float* __restrict__ beta,
    const float* __restrict__ W_out, const float* __restrict__ b_out,
    float* __restrict__ out)
{
    int w = threadIdx.x >> 6, lane = threadIdx.x & 63;
    int r = blockIdx.x * 4 + w;
    float mean = stats[lane] * (1.0f / BNROWS);
    float var = stats[DD + lane] * (1.0f / BNROWS) - mean * mean;
    float rs = rsqrtf(var + 1e-5f);
    float y = (out_pre[(size_t)r * DD + lane] - mean) * rs * gamma[lane] + beta[lane];
    y = y > 0.f ? y : 0.f;
    float p = wave_sum(y * W_out[lane]);
    if (lane == 0) out[r] = p + b_out[0];
}

extern "C" void kernel_launch(void* const* d_in, const int* in_sizes, int n_in,
                              void* d_out, int out_size, void* d_ws, size_t ws_size,
                              hipStream_t stream)
{
    const float* data     = (const float*)d_in[0];
    const float* gumbel   = (const float*)d_in[1];
    const float* W_cond   = (const float*)d_in[2];
    const float* b_cond   = (const float*)d_in[3];
    const float* W_ap     = (const float*)d_in[4];
    const float* b_ap     = (const float*)d_in[5];
    const float* W_av     = (const float*)d_in[6];
    const float* W_r      = (const float*)d_in[7];
    const float* b_r      = (const float*)d_in[8];
    const float* e_base   = (const float*)d_in[9];
    const float* lr_u     = (const float*)d_in[10];
    const float* lr_v     = (const float*)d_in[11];
    const float* W_gnn    = (const float*)d_in[12];
    const float* att_i    = (const float*)d_in[13];
    const float* att_j    = (const float*)d_in[14];
    const float* att_em_i = (const float*)d_in[15];
    const float* att_em_j = (const float*)d_in[16];
    const float* b_gnn    = (const float*)d_in[17];
    const float* bn1_g    = (const float*)d_in[18];
    const float* bn1_b    = (const float*)d_in[19];
    const float* net      = (const float*)d_in[20];
    const float* bno_g    = (const float*)d_in[21];
    const float* bno_b    = (const float*)d_in[22];
    const float* W_out    = (const float*)d_in[23];
    const float* b_out    = (const float*)d_in[24];

    float* ws = (float*)d_ws;
    float* x_lin   = ws + OFF_XLIN;
    float* mixed   = ws + OFF_MIXED;
    float* s_i     = ws + OFF_SI;
    float* s_j     = ws + OFF_SJ;
    float* gnn_pre = ws + OFF_GNN;
    float* out_pre = ws + OFF_OUTP;
    float* stats   = ws + OFF_STAT;          // 256 stats
    float* pnum    = stats + 256;            // 2048
    float* pden    = stats + 2304;           // 32

    float* out0    = (float*)d_out;
    float* h_sys   = out0 + BB * NN;              // 32768
    float* pi_soft = out0 + BB * NN + BB * DD;    // 34816

    // zero stats + pool accumulators (one graph node, no race with k_rows atomics)
    hipMemsetAsync(stats, 0, 2336 * sizeof(float), stream);

    k_rows<<<BNROWS / 4, 256, 0, stream>>>(data, W_cond, b_cond, W_ap, b_ap, W_av, W_gnn,
                                           x_lin, pnum, pden);
    k_mixed<<<BNROWS / 4, 256, 0, stream>>>(e_base, lr_u, lr_v, pnum, pden, gumbel, W_r, b_r,
                                            x_lin, att_i, att_j, att_em_i, att_em_j,
                                            mixed, s_i, s_j, h_sys, pi_soft);

    // ---- chunked score GEMM + fused selection/GAT ----
    size_t ws_floats = ws_size / 4;
    size_t avail = ws_floats > OFF_SC ? ws_floats - OFF_SC : 0;
    int cb = (int)(avail / (size_t)(NN * NN));
    if (cb > BB) cb = BB;
    float* sc = ws + OFF_SC;
    if (cb < 1) { cb = 2; sc = ws + OFF_HIT; }   // free 8MB region
    for (int b0 = 0; b0 < BB; b0 += cb) {
        int c = (BB - b0) < cb ? (BB - b0) : cb;
        k_score<<<c * 64, 256, 0, stream>>>(mixed + (size_t)b0 * NN * DD, sc);
        k_selgat<<<c * 256, 256, 0, stream>>>(sc, b0, x_lin, s_i, s_j, b_gnn, gnn_pre, stats);
    }

    k_bn1<<<256, 256, 0, stream>>>(gnn_pre, stats, bn1_g, bn1_b, net, out_pre);
    k_head<<<BNROWS / 4, 256, 0, stream>>>(out_pre, stats + 128, bno_g, bno_b, W_out, b_out, out0);
}

// Round 12
// 399.900 us; speedup vs baseline: 2.2668x; 1.3563x over previous
//
#include <hip/hip_runtime.h>
#include <math.h>

#define BB 32
#define NN 1024
#define FF 10
#define DD 64
#define MM 4
#define RR 8
#define KK 20
#define BNROWS (BB*NN)   // 32768

// ---- workspace layout (float offsets) ----
#define OFF_HIT   0ull           // free region (sc fallback)  2097152
#define OFF_XLIN  2097152ull     // x_lin  [B,N,D]  2097152
#define OFF_MIXED 4227200ull     // mixed  [B,N,D]  2097152
#define OFF_SI    6324352ull     // s_i    [B,N]    32768
#define OFF_SJ    6357120ull     // s_j    [B,N]    32768
#define OFF_GNN   7700608ull     // gnn_pre [B,N,D] 2097152
#define OFF_OUTP  9797760ull     // out_pre [B,N,D] 2097152
#define OFF_STAT  11894912ull    // stats 256 + pool num 2048 + pool den 32
#define OFF_SC    (OFF_STAT + 2560ull)  // score buffer (if ws large enough)

__device__ __forceinline__ float wave_sum(float v) {
    #pragma unroll
    for (int off = 32; off; off >>= 1) v += __shfl_xor(v, off);
    return v;
}
__device__ __forceinline__ float wave_max(float v) {
    #pragma unroll
    for (int off = 32; off; off >>= 1) v = fmaxf(v, __shfl_xor(v, off));
    return v;
}

// ---------------- K1: rows (x_lin) + fused attention-pool partials ----------------
__global__ __launch_bounds__(256) void k_rows(
    const float* __restrict__ data, const float* __restrict__ W_cond,
    const float* __restrict__ b_cond, const float* __restrict__ W_ap,
    const float* __restrict__ b_ap, const float* __restrict__ W_av,
    const float* __restrict__ W_gnn,
    float* __restrict__ x_lin, float* __restrict__ pnum, float* __restrict__ pden)
{
    int w = threadIdx.x >> 6, lane = threadIdx.x & 63;
    int r = blockIdx.x * 4 + w;               // 4 rows/block, same b
    int b = r >> 10;
    const float* dr = data + r * FF;
    float df[FF];
    #pragma unroll
    for (int f = 0; f < FF; f++) df[f] = dr[f];
    float h = b_cond[lane], x = 0.f;
    #pragma unroll
    for (int f = 0; f < FF; f++) {
        h = fmaf(df[f], W_cond[f * DD + lane], h);
        x = fmaf(df[f], W_gnn[f * DD + lane], x);
    }
    x_lin[r * DD + lane] = x;
    float acc = b_ap[lane];
    #pragma unroll
    for (int e2 = 0; e2 < DD; e2++)
        acc = fmaf(__shfl(h, e2), W_ap[e2 * DD + lane], acc);
    float lr = acc > 0.f ? acc : 0.2f * acc;
    float ep = wave_sum(lr * W_av[lane]);     // all lanes hold e_it[r]
    float wgt = expf(ep);

    __shared__ float pa[4][DD];
    __shared__ float pd[4];
    pa[w][lane] = wgt * h;
    if (lane == 0) pd[w] = wgt;
    __syncthreads();
    if (w == 0) {
        float s = pa[0][lane] + pa[1][lane] + pa[2][lane] + pa[3][lane];
        atomicAdd(&pnum[b * DD + lane], s);
        if (lane == 0) atomicAdd(&pden[b], pd[0] + pd[1] + pd[2] + pd[3]);
    }
}

// ---------------- K2: mixed + s_i/s_j, routing computed inline per block ----------------
__global__ __launch_bounds__(256) void k_mixed(
    const float* __restrict__ e_base, const float* __restrict__ lr_u,
    const float* __restrict__ lr_v,
    const float* __restrict__ pnum, const float* __restrict__ pden,
    const float* __restrict__ gumbel, const float* __restrict__ W_r,
    const float* __restrict__ b_r,
    const float* __restrict__ x_lin,
    const float* __restrict__ att_i, const float* __restrict__ att_j,
    const float* __restrict__ att_em_i, const float* __restrict__ att_em_j,
    float* __restrict__ mixed, float* __restrict__ s_i, float* __restrict__ s_j,
    float* __restrict__ h_sys, float* __restrict__ pi_soft)
{
    int t = threadIdx.x, w = t >> 6, lane = t & 63;
    int r = blockIdx.x * 4 + w;
    int b = r >> 10, n = r & 1023;

    // --- routing for this block's b (redundant per block, deterministic) ---
    float inv = 1.0f / pden[b];
    float lg[MM];
    #pragma unroll
    for (int m = 0; m < MM; m++) lg[m] = b_r[m] + gumbel[b * MM + m];
    for (int d = 0; d < DD; d++) {
        float hv = pnum[b * DD + d] * inv;
        #pragma unroll
        for (int m = 0; m < MM; m++) lg[m] = fmaf(hv, W_r[d * MM + m], lg[m]);
    }
    float mxl = fmaxf(fmaxf(lg[0], lg[1]), fmaxf(lg[2], lg[3]));
    float sp = 0.f, p[MM];
    #pragma unroll
    for (int m = 0; m < MM; m++) { p[m] = expf(lg[m] - mxl); sp += p[m]; }
    #pragma unroll
    for (int m = 0; m < MM; m++) p[m] /= sp;
    int i1 = 0; float v1 = p[0];
    #pragma unroll
    for (int m = 1; m < MM; m++) if (p[m] > v1) { v1 = p[m]; i1 = m; }
    int i2 = -1; float v2 = -1.f;
    #pragma unroll
    for (int m = 0; m < MM; m++) if (m != i1 && p[m] > v2) { v2 = p[m]; i2 = m; }
    float norm = fmaxf(v1 + v2, 1e-12f);
    float pt[MM];
    #pragma unroll
    for (int m = 0; m < MM; m++)
        pt[m] = (m == i1 ? v1 : (m == i2 ? v2 : 0.f)) / norm;

    // --- block 0 emits h_sys + pi_soft ---
    if (blockIdx.x == 0) {
        for (int i = t; i < BB * DD; i += 256)
            h_sys[i] = pnum[i] / pden[i >> 6];
        if (t < BB) {
            int b2 = t;
            float inv2 = 1.0f / pden[b2];
            float lg2[MM];
            #pragma unroll
            for (int m = 0; m < MM; m++) lg2[m] = b_r[m] + gumbel[b2 * MM + m];
            for (int d = 0; d < DD; d++) {
                float hv = pnum[b2 * DD + d] * inv2;
                #pragma unroll
                for (int m = 0; m < MM; m++) lg2[m] = fmaf(hv, W_r[d * MM + m], lg2[m]);
            }
            float mx2 = fmaxf(fmaxf(lg2[0], lg2[1]), fmaxf(lg2[2], lg2[3]));
            float s2 = 0.f, p2[MM];
            #pragma unroll
            for (int m = 0; m < MM; m++) { p2[m] = expf(lg2[m] - mx2); s2 += p2[m]; }
            #pragma unroll
            for (int m = 0; m < MM; m++) pi_soft[b2 * MM + m] = p2[m] / s2;
        }
    }

    // --- mixed + s_i/s_j ---
    float LR[MM];
    #pragma unroll
    for (int m = 0; m < MM; m++) {
        float a = 0.f;
        #pragma unroll
        for (int rr = 0; rr < RR; rr++)
            a = fmaf(lr_u[(m * NN + n) * RR + rr], lr_v[(m * RR + rr) * DD + lane], a);
        LR[m] = a;
    }
    float eb = e_base[n * DD + lane];
    float mx = 0.f;
    #pragma unroll
    for (int m = 0; m < MM; m++) mx = fmaf(pt[m], eb + LR[m], mx);
    mixed[(size_t)r * DD + lane] = mx;
    float x = x_lin[(size_t)r * DD + lane];
    float r1 = wave_sum(x * att_i[lane] + mx * att_em_i[lane]);
    float r2 = wave_sum(x * att_j[lane] + mx * att_em_j[lane]);
    if (lane == 0) { s_i[r] = r1; s_j[r] = r2; }
}

// ---------------- K3: score GEMM, 128x128 tile, K in four 16-wide stages ----------------
__global__ __launch_bounds__(256) void k_score(
    const float* __restrict__ mixed_chunk, float* __restrict__ sc)
{
    __shared__ float As[16 * 132];
    __shared__ float Bs[16 * 132];
    int t = threadIdx.x;
    int bb = blockIdx.x >> 6;
    int rr = blockIdx.x & 63;
    int it = rr >> 3, jt = rr & 7;
    int i0 = it * 128, j0 = jt * 128;
    const float* mb = mixed_chunk + (size_t)bb * NN * DD;

    int tx = t & 15, ty = t >> 4;
    float acc[8][8];
    #pragma unroll
    for (int a = 0; a < 8; a++)
        #pragma unroll
        for (int bj = 0; bj < 8; bj++) acc[a][bj] = 0.f;

    int rowi[2], qi[2], swi[2];
    #pragma unroll
    for (int c = 0; c < 2; c++) {
        int id = t + c * 256;                 // 0..511
        qi[c] = (id >> 4) & 3;
        rowi[c] = (id & 15) | ((id >> 6) << 4);
        swi[c] = ((rowi[c] & 4) << 4) | ((rowi[c] >> 3) << 2) | (rowi[c] & 3);
    }
    float4 pa[2], pb[2];
    #pragma unroll
    for (int c = 0; c < 2; c++) {             // prefetch stage 0
        pa[c] = *(const float4*)(mb + (size_t)(i0 + rowi[c]) * DD + qi[c] * 4);
        pb[c] = *(const float4*)(mb + (size_t)(j0 + rowi[c]) * DD + qi[c] * 4);
    }
    #pragma unroll
    for (int st = 0; st < 4; st++) {
        if (st) __syncthreads();
        #pragma unroll
        for (int c = 0; c < 2; c++) {
            int pos = qi[c] * 4 * 132 + swi[c];
            As[pos] = pa[c].x; As[pos + 132] = pa[c].y; As[pos + 264] = pa[c].z; As[pos + 396] = pa[c].w;
            Bs[pos] = pb[c].x; Bs[pos + 132] = pb[c].y; Bs[pos + 264] = pb[c].z; Bs[pos + 396] = pb[c].w;
        }
        __syncthreads();
        if (st < 3) {                          // prefetch next stage during compute
            #pragma unroll
            for (int c = 0; c < 2; c++) {
                pa[c] = *(const float4*)(mb + (size_t)(i0 + rowi[c]) * DD + (st + 1) * 16 + qi[c] * 4);
                pb[c] = *(const float4*)(mb + (size_t)(j0 + rowi[c]) * DD + (st + 1) * 16 + qi[c] * 4);
            }
        }
        #pragma unroll 4
        for (int d = 0; d < 16; d++) {
            float4 a0 = *(const float4*)&As[d * 132 + ty * 4];
            float4 a1 = *(const float4*)&As[d * 132 + 64 + ty * 4];
            float4 b0 = *(const float4*)&Bs[d * 132 + tx * 4];
            float4 b1 = *(const float4*)&Bs[d * 132 + 64 + tx * 4];
            float av[8] = {a0.x, a0.y, a0.z, a0.w, a1.x, a1.y, a1.z, a1.w};
            float bv[8] = {b0.x, b0.y, b0.z, b0.w, b1.x, b1.y, b1.z, b1.w};
            #pragma unroll
            for (int a = 0; a < 8; a++)
                #pragma unroll
                for (int bj = 0; bj < 8; bj++)
                    acc[a][bj] = fmaf(av[a], bv[bj], acc[a][bj]);
        }
    }

    float* out = sc + ((size_t)bb * NN + i0 + ty * 8) * NN + j0 + tx * 8;
    #pragma unroll
    for (int a = 0; a < 8; a++) {
        float4 o0 = {acc[a][0], acc[a][1], acc[a][2], acc[a][3]};
        float4 o1 = {acc[a][4], acc[a][5], acc[a][6], acc[a][7]};
        *(float4*)(out + (size_t)a * NN) = o0;
        *(float4*)(out + (size_t)a * NN + 4) = o1;
    }
}

// ---------------- K4: fused top-20 selection + GAT (R5 body, NO stats atomics) ----------------
__global__ __launch_bounds__(256) void k_selgat(
    const float* __restrict__ sc, int b0,
    const float* __restrict__ x_lin, const float* __restrict__ s_i,
    const float* __restrict__ s_j, const float* __restrict__ b_gnn,
    float* __restrict__ gnn_pre)
{
    int w = threadIdx.x >> 6, lane = threadIdx.x & 63;
    int lr = blockIdx.x * 4 + w;
    int r = b0 * NN + lr;
    int b = r >> 10, n = r & 1023;
    const float* row = sc + (size_t)lr * NN;

    unsigned uk[16];
    #pragma unroll
    for (int c = 0; c < 4; c++) {
        float4 v = *(const float4*)(row + c * 256 + lane * 4);
        float vv[4] = {v.x, v.y, v.z, v.w};
        #pragma unroll
        for (int q = 0; q < 4; q++) {
            unsigned u = __float_as_uint(vv[q]);
            uk[c * 4 + q] = u ^ (((unsigned)((int)u >> 31)) | 0x80000000u);
        }
    }
    unsigned mx = uk[0];
    #pragma unroll
    for (int i = 1; i < 16; i++) mx = uk[i] > mx ? uk[i] : mx;
    unsigned sv = mx;
    #pragma unroll
    for (int blk = 2; blk <= 64; blk <<= 1) {
        #pragma unroll
        for (int dist = blk >> 1; dist >= 1; dist >>= 1) {
            unsigned pv = (unsigned)__shfl_xor((int)sv, dist);
            bool up = (lane & blk) == 0;
            bool upper = (lane & dist) == 0;
            bool g = sv > pv;
            sv = (((g == upper) == up)) ? sv : pv;
        }
    }
    unsigned tau = (unsigned)__shfl((int)sv, 19);

    __shared__ unsigned skey[4][64];
    __shared__ int sjj[4][64];
    int base = 0;
    #pragma unroll
    for (int s = 0; s < 16; s++) {
        bool q = uk[s] >= tau;
        unsigned long long m = __ballot(q);
        if (q) {
            int pos = base + __popcll(m & ((1ull << lane) - 1ull));
            if (pos < 64) {
                skey[w][pos] = uk[s];
                sjj[w][pos] = ((s >> 2) << 8) + lane * 4 + (s & 3);
            }
        }
        base += __popcll(m);
    }
    int C = base;

    float vk = -INFINITY; int ik = 0;
    if (C <= 64) {
        unsigned ck = 0u; int cj = 0x7FFFFFFF;
        if (lane < C) { ck = skey[w][lane]; cj = sjj[w][lane]; }
        if (C <= 32) {
            #pragma unroll
            for (int blk = 2; blk <= 32; blk <<= 1)
                #pragma unroll
                for (int dist = blk >> 1; dist >= 1; dist >>= 1) {
                    unsigned pk = (unsigned)__shfl_xor((int)ck, dist);
                    int pj = __shfl_xor(cj, dist);
                    bool up = (lane & blk) == 0;
                    bool upper = (lane & dist) == 0;
                    bool g = (ck > pk) || (ck == pk && cj < pj);
                    bool keep = ((g == upper) == up);
                    ck = keep ? ck : pk; cj = keep ? cj : pj;
                }
        } else {
            #pragma unroll
            for (int blk = 2; blk <= 64; blk <<= 1)
                #pragma unroll
                for (int dist = blk >> 1; dist >= 1; dist >>= 1) {
                    unsigned pk = (unsigned)__shfl_xor((int)ck, dist);
                    int pj = __shfl_xor(cj, dist);
                    bool up = (lane & blk) == 0;
                    bool upper = (lane & dist) == 0;
                    bool g = (ck > pk) || (ck == pk && cj < pj);
                    bool keep = ((g == upper) == up);
                    ck = keep ? ck : pk; cj = keep ? cj : pj;
                }
        }
        if (lane < KK) {
            unsigned u = (ck & 0x80000000u) ? (ck ^ 0x80000000u) : ~ck;
            vk = __uint_as_float(u);
            ik = cj;
        }
    } else {
        for (int k = 0; k < KK; k++) {
            unsigned bm = uk[0]; int bsl = 0;
            #pragma unroll
            for (int i = 1; i < 16; i++) if (uk[i] > bm) { bm = uk[i]; bsl = i; }
            unsigned wm = bm;
            #pragma unroll
            for (int off = 32; off; off >>= 1) {
                unsigned tt = (unsigned)__shfl_xor((int)wm, off);
                wm = tt > wm ? tt : wm;
            }
            unsigned long long ball = __ballot(bm == wm);
            int winner = (int)__builtin_ctzll(ball);
            int slotw = __shfl(bsl, winner);
            int jw = ((slotw >> 2) << 8) + winner * 4 + (slotw & 3);
            unsigned u2 = (wm & 0x80000000u) ? (wm ^ 0x80000000u) : ~wm;
            if (lane == k) { vk = __uint_as_float(u2); ik = jw; }
            if (lane == winner) uk[bsl] = 0u;
        }
    }

    float m1 = wave_max(vk);
    float ek = (lane < KK) ? expf(vk - m1) : 0.f;
    float s1v = wave_sum(ek);
    float wk = ek / s1v;
    float si = s_i[r], sjn = s_j[r];
    float a = -INFINITY;
    if (lane < KK) {
        float sjk = s_j[(b << 10) + ik];
        float t2 = si + sjk;
        a = (ik == n) ? -INFINITY : (t2 > 0.f ? t2 : 0.2f * t2);
    }
    float ts = si + sjn;
    float aself = ts > 0.f ? ts : 0.2f * ts;
    float am = wave_max(fmaxf(a, aself));
    float ea = (lane < KK && a != -INFINITY) ? expf(a - am) : 0.f;
    float es = expf(aself - am);
    float ssum = wave_sum(ea) + es;
    float wnb = (ea / ssum) * wk;
    float wself = es / ssum;
    float accg = b_gnn[lane] + wself * x_lin[(size_t)r * DD + lane];
    #pragma unroll
    for (int k = 0; k < KK; k++) {
        int jk = __shfl(ik, k);
        float wv = __shfl(wnb, k);
        accg = fmaf(wv, x_lin[((size_t)(b << 10) + jk) * DD + lane], accg);
    }
    gnn_pre[(size_t)r * DD + lane] = accg;
}

// ---------------- K5: per-channel sum/sumsq over gnn_pre (256 blocks, low atomic fan-in) ----------------
__global__ __launch_bounds__(256) void k_stats(const float* __restrict__ src, float* __restrict__ sums)
{
    int w = threadIdx.x >> 6, lane = threadIdx.x & 63;
    __shared__ float ps[4][DD], pq[4][DD];
    float s = 0.f, q = 0.f;
    int base = blockIdx.x * 128;
    for (int i = w; i < 128; i += 4) {
        float v = src[(size_t)(base + i) * DD + lane];
        s += v; q = fmaf(v, v, q);
    }
    ps[w][lane] = s; pq[w][lane] = q;
    __syncthreads();
    if (w == 0) {
        s = ps[0][lane] + ps[1][lane] + ps[2][lane] + ps[3][lane];
        q = pq[0][lane] + pq[1][lane] + pq[2][lane] + pq[3][lane];
        atomicAdd(&sums[lane], s);
        atomicAdd(&sums[DD + lane], q);
    }
}

// ---------------- K6: bn1 + relu + embed multiply (+ bno stats partials) ----------------
__global__ __launch_bounds__(256) void k_bn1(
    const float* __restrict__ gnn_pre, float* __restrict__ stats,
    const float* __restrict__ gamma, const float* __restrict__ beta,
    const float* __restrict__ net, float* __restrict__ out_pre)
{
    int tid = threadIdx.x;
    int d0 = (tid & 15) * 4;
    float mean4[4], rs4[4], bt4[4];
    #pragma unroll
    for (int k = 0; k < 4; k++) {
        float mu = stats[d0 + k] * (1.0f / BNROWS);
        float var = stats[64 + d0 + k] * (1.0f / BNROWS) - mu * mu;
        mean4[k] = mu;
        rs4[k] = rsqrtf(var + 1e-5f) * gamma[d0 + k];
        bt4[k] = beta[d0 + k];
    }
    float s4[4] = {0, 0, 0, 0}, q4[4] = {0, 0, 0, 0};
    size_t base4 = (size_t)blockIdx.x * 2048;
    #pragma unroll
    for (int i = 0; i < 8; i++) {
        size_t f4 = base4 + (size_t)i * 256 + tid;
        float4 v = ((const float4*)gnn_pre)[f4];
        int n = ((int)(f4 >> 4)) & 1023;
        float4 nv = ((const float4*)net)[(size_t)n * 16 + (tid & 15)];
        float vv[4] = {v.x, v.y, v.z, v.w};
        float nn2[4] = {nv.x, nv.y, nv.z, nv.w};
        float ov[4];
        #pragma unroll
        for (int k = 0; k < 4; k++) {
            float y = (vv[k] - mean4[k]) * rs4[k] + bt4[k];
            y = y > 0.f ? y : 0.f;
            float o = y * nn2[k];
            ov[k] = o;
            s4[k] += o;
            q4[k] = fmaf(o, o, q4[k]);
        }
        float4 o4 = {ov[0], ov[1], ov[2], ov[3]};
        ((float4*)out_pre)[f4] = o4;
    }
    __shared__ float4 ls[256], lq[256];
    ls[tid] = make_float4(s4[0], s4[1], s4[2], s4[3]);
    lq[tid] = make_float4(q4[0], q4[1], q4[2], q4[3]);
    __syncthreads();
    if (tid < 16) {
        float4 S = ls[tid], Q = lq[tid];
        #pragma unroll
        for (int rr = 1; rr < 16; rr++) {
            float4 a = ls[tid + 16 * rr], b = lq[tid + 16 * rr];
            S.x += a.x; S.y += a.y; S.z += a.z; S.w += a.w;
            Q.x += b.x; Q.y += b.y; Q.z += b.z; Q.w += b.w;
        }
        atomicAdd(&stats[128 + tid * 4 + 0], S.x);
        atomicAdd(&stats[128 + tid * 4 + 1], S.y);
        atomicAdd(&stats[128 + tid * 4 + 2], S.z);
        atomicAdd(&stats[128 + tid * 4 + 3], S.w);
        atomicAdd(&stats[192 + tid * 4 + 0], Q.x);
        atomicAdd(&stats[192 + tid * 4 + 1], Q.y);
        atomicAdd(&stats[192 + tid * 4 + 2], Q.z);
        atomicAdd(&stats[192 + tid * 4 + 3], Q.w);
    }
}

// ---------------- K7: bn_out + relu + head ----------------
__global__ __launch_bounds__(256) void k_head(
    const float* __restrict__ out_pre, const float* __restrict__ stats,
    const float* __restrict__ gamma, const float* __restrict__ beta,
    const float* __restrict__ W_out, const float* __restrict__ b_out,
    float* __restrict__ out)
{
    int w = threadIdx.x >> 6, lane = threadIdx.x & 63;
    int r = blockIdx.x * 4 + w;
    float mean = stats[lane] * (1.0f / BNROWS);
    float var = stats[DD + lane] * (1.0f / BNROWS) - mean * mean;
    float rs = rsqrtf(var + 1e-5f);
    float y = (out_pre[(size_t)r * DD + lane] - mean) * rs * gamma[lane] + beta[lane];
    y = y > 0.f ? y : 0.f;
    float p = wave_sum(y * W_out[lane]);
    if (lane == 0) out[r] = p + b_out[0];
}

extern "C" void kernel_launch(void* const* d_in, const int* in_sizes, int n_in,
                              void* d_out, int out_size, void* d_ws, size_t ws_size,
                              hipStream_t stream)
{
    const float* data     = (const float*)d_in[0];
    const float* gumbel   = (const float*)d_in[1];
    const float* W_cond   = (const float*)d_in[2];
    const float* b_cond   = (const float*)d_in[3];
    const float* W_ap     = (const float*)d_in[4];
    const float* b_ap     = (const float*)d_in[5];
    const float* W_av     = (const float*)d_in[6];
    const float* W_r      = (const float*)d_in[7];
    const float* b_r      = (const float*)d_in[8];
    const float* e_base   = (const float*)d_in[9];
    const float* lr_u     = (const float*)d_in[10];
    const float* lr_v     = (const float*)d_in[11];
    const float* W_gnn    = (const float*)d_in[12];
    const float* att_i    = (const float*)d_in[13];
    const float* att_j    = (const float*)d_in[14];
    const float* att_em_i = (const float*)d_in[15];
    const float* att_em_j = (const float*)d_in[16];
    const float* b_gnn    = (const float*)d_in[17];
    const float* bn1_g    = (const float*)d_in[18];
    const float* bn1_b    = (const float*)d_in[19];
    const float* net      = (const float*)d_in[20];
    const float* bno_g    = (const float*)d_in[21];
    const float* bno_b    = (const float*)d_in[22];
    const float* W_out    = (const float*)d_in[23];
    const float* b_out    = (const float*)d_in[24];

    float* ws = (float*)d_ws;
    float* x_lin   = ws + OFF_XLIN;
    float* mixed   = ws + OFF_MIXED;
    float* s_i     = ws + OFF_SI;
    float* s_j     = ws + OFF_SJ;
    float* gnn_pre = ws + OFF_GNN;
    float* out_pre = ws + OFF_OUTP;
    float* stats   = ws + OFF_STAT;          // 256 stats
    float* pnum    = stats + 256;            // 2048
    float* pden    = stats + 2304;           // 32

    float* out0    = (float*)d_out;
    float* h_sys   = out0 + BB * NN;              // 32768
    float* pi_soft = out0 + BB * NN + BB * DD;    // 34816

    hipMemsetAsync(stats, 0, 2336 * sizeof(float), stream);

    k_rows<<<BNROWS / 4, 256, 0, stream>>>(data, W_cond, b_cond, W_ap, b_ap, W_av, W_gnn,
                                           x_lin, pnum, pden);
    k_mixed<<<BNROWS / 4, 256, 0, stream>>>(e_base, lr_u, lr_v, pnum, pden, gumbel, W_r, b_r,
                                            x_lin, att_i, att_j, att_em_i, att_em_j,
                                            mixed, s_i, s_j, h_sys, pi_soft);

    // ---- chunked score GEMM + fused selection/GAT ----
    size_t ws_floats = ws_size / 4;
    size_t avail = ws_floats > OFF_SC ? ws_floats - OFF_SC : 0;
    int cb = (int)(avail / (size_t)(NN * NN));
    if (cb > BB) cb = BB;
    float* sc = ws + OFF_SC;
    if (cb < 1) { cb = 2; sc = ws + OFF_HIT; }   // free 8MB region
    for (int b0 = 0; b0 < BB; b0 += cb) {
        int c = (BB - b0) < cb ? (BB - b0) : cb;
        k_score<<<c * 64, 256, 0, stream>>>(mixed + (size_t)b0 * NN * DD, sc);
        k_selgat<<<c * 256, 256, 0, stream>>>(sc, b0, x_lin, s_i, s_j, b_gnn, gnn_pre);
    }

    k_stats<<<256, 256, 0, stream>>>(gnn_pre, stats);
    k_bn1<<<256, 256, 0, stream>>>(gnn_pre, stats, bn1_g, bn1_b, net, out_pre);
    k_head<<<BNROWS / 4, 256, 0, stream>>>(out_pre, stats + 128, bno_g, bno_b, W_out, b_out, out0);
}